// Round 13
// baseline (716.201 us; speedup 1.0000x reference)
//
#include <hip/hip_runtime.h>
#include <math.h>

constexpr int Nn  = 4096;
constexpr int Ne  = 32768;
constexpr int NEf = Ne + Nn;     // real edges + self loops

// ---------------- ws layout (float offsets) ----------------
// R0 [0..2097152)        X fp32 (prep/L1) -> wt1 hi/lo bf16 (L1 gemm) -> whi fp16 [2048][2048] (L2 loop)
// R1 [2097152..10485760) z1 hi/lo bf16 (L1) -> x3 fp16 [4096][2048] (head loop) -> part fp32 (final)
// R2 [10485760..18874368) x2hi/x2lo fp16 [4096][2048] (written by L1 gemm epilogue)
// R3 [18874368..23068672) H fp16 [4096][2048] (L2 loop)
// R5 [25165824..27262976) wtout hi/lo fp16 [256][8192]
// R6 [27262976..31457280) YP 4x [4096][256] fp32
constexpr size_t OFF_X    = 0;
constexpr size_t OFF_WT1H = 0;
constexpr size_t OFF_WT1L = 524288;
constexpr size_t OFF_Z1HI = 2097152;
constexpr size_t OFF_Z1LO = 6291456;
constexpr size_t OFF_X3   = 2097152;     // ushort region (fp16), overlays dead z1
constexpr size_t OFF_PART = 2097152;     // fp32, overlays dead x3 (final)
constexpr size_t OFF_X2HI = 10485760;    // ushort region
constexpr size_t OFF_X2LO = 14680064;    // ushort region
constexpr size_t OFF_H    = 18874368;    // ushort region (fp16) [4096][2048]
constexpr size_t OFF_WOH  = 25165824;    // ushort region [256][8192] fp16
constexpr size_t OFF_WOL  = 26214400;    // ushort region
constexpr size_t OFF_YP   = 27262976;
constexpr size_t OFF_LP  = 31457280;     // [N,16] self-loop edge attr
constexpr size_t OFF_WS1 = OFF_LP  + 65536;   // [512,4]
constexpr size_t OFF_WD1 = OFF_WS1 + 2048;    // [512,4]
constexpr size_t OFF_WS2 = OFF_WD1 + 2048;    // [2048,4]
constexpr size_t OFF_WD2 = OFF_WS2 + 8192;    // [2048,4]
constexpr size_t OFF_AE1 = OFF_WD2 + 8192;    // [16,4]
constexpr size_t OFF_AE2 = OFF_AE1 + 64;      // [16,4]
constexpr size_t OFF_AS1 = OFF_AE2 + 64;      // [N,4]
constexpr size_t OFF_AD1 = OFF_AS1 + 16384;
constexpr size_t OFF_AS2 = OFF_AD1 + 16384;
constexpr size_t OFF_AD2 = OFF_AS2 + 16384;
constexpr size_t OFF_EB  = OFF_AD2 + 16384;          // [Ef,4] logits
constexpr size_t OFF_AL  = OFF_EB  + (size_t)NEf*4;  // [Ef,4] alpha
constexpr size_t OFF_I   = OFF_AL  + (size_t)NEf*4;  // int region
constexpr size_t I_DEG = 0;       // [N]
constexpr size_t I_RP  = 4096;    // [N+1] (+pad)
constexpr size_t I_CUR = 8200;    // [N]
constexpr size_t I_EID = 12296;   // [Ef]
constexpr size_t WS_FLOATS = OFF_I + I_EID + (size_t)NEf + 64;

using bf16x8 = __bf16 __attribute__((ext_vector_type(8)));
using f16x8  = _Float16 __attribute__((ext_vector_type(8)));
using f32x4  = float __attribute__((ext_vector_type(4)));

__device__ __forceinline__ float wred64(float v){
#pragma unroll
  for (int o = 32; o > 0; o >>= 1) v += __shfl_down(v, o, 64);
  return v;
}
__device__ __forceinline__ float lrelu(float v, float s){ return v > 0.f ? v : s * v; }

__device__ __forceinline__ unsigned short f2bf(float x){  // RTNE
  unsigned int u = __float_as_uint(x);
  unsigned int r = (u + 0x7FFFu + ((u >> 16) & 1u)) >> 16;
  return (unsigned short)r;
}
__device__ __forceinline__ float bf2f(unsigned short h){
  return __uint_as_float((unsigned int)h << 16);
}
__device__ __forceinline__ void split2(float x, unsigned short& h, unsigned short& l){
  h = f2bf(x);
  l = f2bf(x - bf2f(h));
}
__device__ __forceinline__ unsigned short f2h(float x){
  _Float16 h = (_Float16)x;
  return __builtin_bit_cast(unsigned short, h);
}
__device__ __forceinline__ float h2f(unsigned short u){
  return (float)__builtin_bit_cast(_Float16, u);
}
__device__ __forceinline__ void split2h(float x, unsigned short& h, unsigned short& l){
  _Float16 hh = (_Float16)x;
  h = __builtin_bit_cast(unsigned short, hh);
  _Float16 ll = (_Float16)(x - (float)hh);
  l = __builtin_bit_cast(unsigned short, ll);
}
__device__ __forceinline__ void gload16(const void* g, void* l){
  __builtin_amdgcn_global_load_lds((const __attribute__((address_space(1))) void*)g,
                                   (__attribute__((address_space(3))) void*)l, 16, 0, 0);
}

// ---------------- small prep kernels ----------------
__global__ void k_concat(const float* __restrict__ xg, const float* __restrict__ ac,
                         const float* __restrict__ ti, float* __restrict__ x){
  int i = blockIdx.x * 256 + threadIdx.x;          // over N*512
  int n = i >> 9, c = i & 511;
  float v;
  if (c < 256)      v = xg[(size_t)n*256 + c];
  else if (c < 384) v = ac[(size_t)n*128 + (c-256)];
  else              v = ti[(size_t)n*128 + (c-384)];
  x[i] = v;
}

__global__ void k_count(const int* __restrict__ ei, int* __restrict__ deg){
  int e = blockIdx.x * 256 + threadIdx.x;
  if (e < Ne) atomicAdd(&deg[ei[Ne + e]], 1);
}

__global__ void k_scan(const int* __restrict__ deg, int* __restrict__ rowptr, int* __restrict__ cursor){
  __shared__ int sd[1024];
  int t = threadIdx.x;
  int v[4]; int s = 0;
#pragma unroll
  for (int i = 0; i < 4; i++){ v[i] = s; s += deg[t*4 + i] + 1; }   // +1 self loop
  sd[t] = s;
  __syncthreads();
  for (int off = 1; off < 1024; off <<= 1){
    int x = (t >= off) ? sd[t - off] : 0;
    __syncthreads();
    sd[t] += x;
    __syncthreads();
  }
  int base = (t == 0) ? 0 : sd[t - 1];
#pragma unroll
  for (int i = 0; i < 4; i++){ int rp = base + v[i]; rowptr[t*4 + i] = rp; cursor[t*4 + i] = rp; }
  if (t == 1023) rowptr[4096] = sd[1023];
}

__global__ void k_fill(const int* __restrict__ ei, int* __restrict__ cursor, int* __restrict__ eids){
  int e = blockIdx.x * 256 + threadIdx.x;
  if (e >= NEf) return;
  int d = (e < Ne) ? ei[Ne + e] : (e - Ne);
  int p = atomicAdd(&cursor[d], 1);
  eids[p] = e;
}

__global__ void k_sort(const int* __restrict__ rowptr, int* __restrict__ eids){
  int n = blockIdx.x * 64 + threadIdx.x;
  if (n >= Nn) return;
  int b = rowptr[n], e = rowptr[n + 1];
  for (int i = b + 1; i < e; i++){
    int key = eids[i]; int j = i - 1;
    while (j >= b && eids[j] > key){ eids[j+1] = eids[j]; j--; }
    eids[j+1] = key;
  }
}

__global__ void k_loopattr(const float* __restrict__ eattr, const int* __restrict__ rowptr,
                           const int* __restrict__ eids, float* __restrict__ lp){
  int idx = blockIdx.x * 256 + threadIdx.x;        // N*16
  int n = idx >> 4, a = idx & 15;
  if (n >= Nn) return;
  int b = rowptr[n], e = rowptr[n + 1];
  float s = 0.f; int cnt = 0;
  for (int j = b; j < e; ++j){
    int id = eids[j];
    if (id < Ne){ s += eattr[(size_t)id*16 + a]; cnt++; }
  }
  lp[(size_t)n*16 + a] = s / fmaxf((float)cnt, 1.f);
}

// Ws[k,h] = sum_c W[k, h*C+c]*a_s[h,c] ; Wd likewise.
__global__ void k_proj(const float* __restrict__ W, const float* __restrict__ a_s,
                       const float* __restrict__ a_d, float* __restrict__ Ws,
                       float* __restrict__ Wd, int K, int C){
  int gid = blockIdx.x * 256 + threadIdx.x;
  int wave = gid >> 6, lane = gid & 63;
  int h = wave & 3, k = wave >> 2;
  if (k >= K) return;
  const float* wrow = W + (size_t)k * (4*C) + (size_t)h * C;
  const float* ar = a_s + (size_t)h * C;
  const float* dr = a_d + (size_t)h * C;
  float ps = 0.f, pd = 0.f;
  for (int c = lane; c < C; c += 64){ float w = wrow[c]; ps += w * ar[c]; pd += w * dr[c]; }
  ps = wred64(ps); pd = wred64(pd);
  if (lane == 0){ Ws[k*4 + h] = ps; Wd[k*4 + h] = pd; }
}

// one wave per (k,h): outp[k*4+h] = dot(We[k, h*C:(h+1)*C], ae[h,:])
__global__ void k_aeproj(const float* __restrict__ We, const float* __restrict__ ae,
                         float* __restrict__ outp, int C){
  int gid = blockIdx.x * 256 + threadIdx.x;
  int wave = gid >> 6, lane = gid & 63;
  int h = wave & 3, k = wave >> 2;
  if (k >= 16) return;
  const float* wrow = We + (size_t)k * (4*C) + (size_t)h * C;
  const float* ar = ae + (size_t)h * C;
  float s = 0.f;
  for (int c = lane; c < C; c += 64) s += wrow[c] * ar[c];
  s = wred64(s);
  if (lane == 0) outp[k*4 + h] = s;
}

// as[n,h], ad[n,h] = x[n,:] @ Ws/Wd. Block per node.
// HALF: x given as fp16 hi/lo pair (reconstructed hi+lo, near-exact).
template<bool HALF>
__global__ __launch_bounds__(256) void k_asad(const void* __restrict__ xp, const void* __restrict__ xlp,
                      const float* __restrict__ Ws,
                      const float* __restrict__ Wd, float* __restrict__ as_,
                      float* __restrict__ ad_, int D){
  int n = blockIdx.x, t = threadIdx.x;
  float p[8] = {0,0,0,0,0,0,0,0};
  if (HALF){
    const unsigned short* rh = (const unsigned short*)xp + (size_t)n * D;
    const unsigned short* rl = (const unsigned short*)xlp + (size_t)n * D;
    for (int c = t; c < D; c += 256){
      float xv = h2f(rh[c]) + h2f(rl[c]);
      float4 ws4 = *(const float4*)&Ws[c*4];
      float4 wd4 = *(const float4*)&Wd[c*4];
      p[0] += xv * ws4.x; p[1] += xv * ws4.y; p[2] += xv * ws4.z; p[3] += xv * ws4.w;
      p[4] += xv * wd4.x; p[5] += xv * wd4.y; p[6] += xv * wd4.z; p[7] += xv * wd4.w;
    }
  } else {
    const float* row = (const float*)xp + (size_t)n * D;
    for (int c = t; c < D; c += 256){
      float xv = row[c];
      float4 ws4 = *(const float4*)&Ws[c*4];
      float4 wd4 = *(const float4*)&Wd[c*4];
      p[0] += xv * ws4.x; p[1] += xv * ws4.y; p[2] += xv * ws4.z; p[3] += xv * ws4.w;
      p[4] += xv * wd4.x; p[5] += xv * wd4.y; p[6] += xv * wd4.z; p[7] += xv * wd4.w;
    }
  }
  __shared__ float sm[4][8];
  int lane = t & 63, wid = t >> 6;
#pragma unroll
  for (int q = 0; q < 8; q++){
    float v = wred64(p[q]);
    if (lane == 0) sm[wid][q] = v;
  }
  __syncthreads();
  if (t < 8){
    float s = sm[0][t] + sm[1][t] + sm[2][t] + sm[3][t];
    if (t < 4) as_[(size_t)n*4 + t] = s;
    else       ad_[(size_t)n*4 + (t-4)] = s;
  }
}

__global__ void k_edge(const float* __restrict__ eattr, const float* __restrict__ lp,
                       const int* __restrict__ ei, const float* __restrict__ as_,
                       const float* __restrict__ ad_, const float* __restrict__ aep,
                       float* __restrict__ ebuf){
  int e = blockIdx.x * 256 + threadIdx.x;
  if (e >= NEf) return;
  int s, d; const float* ea;
  if (e < Ne){ s = ei[e]; d = ei[Ne + e]; ea = eattr + (size_t)e * 16; }
  else { s = e - Ne; d = e - Ne; ea = lp + (size_t)(e - Ne) * 16; }
  float eav[16];
#pragma unroll
  for (int k = 0; k < 16; k++) eav[k] = ea[k];
#pragma unroll
  for (int h = 0; h < 4; h++){
    float v = as_[(size_t)s*4 + h] + ad_[(size_t)d*4 + h];
#pragma unroll
    for (int k = 0; k < 16; k++) v += eav[k] * aep[k*4 + h];
    ebuf[(size_t)e*4 + h] = lrelu(v, 0.2f);
  }
}

// wave-per-node softmax: 4 waves/block, 1024 blocks.
__global__ __launch_bounds__(256) void k_softmax(const int* __restrict__ rowptr, const int* __restrict__ eids,
                          const float* __restrict__ ebuf, float* __restrict__ alpha){
  const int wid = threadIdx.x >> 6, lane = threadIdx.x & 63;
  const int n = blockIdx.x * 4 + wid;
  const int b = rowptr[n], e = rowptr[n + 1];
  float4 m = {-1e30f, -1e30f, -1e30f, -1e30f};
  for (int j = b + lane; j < e; j += 64){
    float4 ev = *(const float4*)&ebuf[(size_t)eids[j]*4];
    m.x = fmaxf(m.x, ev.x); m.y = fmaxf(m.y, ev.y);
    m.z = fmaxf(m.z, ev.z); m.w = fmaxf(m.w, ev.w);
  }
#pragma unroll
  for (int o = 32; o > 0; o >>= 1){
    m.x = fmaxf(m.x, __shfl_xor(m.x, o, 64));
    m.y = fmaxf(m.y, __shfl_xor(m.y, o, 64));
    m.z = fmaxf(m.z, __shfl_xor(m.z, o, 64));
    m.w = fmaxf(m.w, __shfl_xor(m.w, o, 64));
  }
  float4 s = {0.f, 0.f, 0.f, 0.f};
  for (int j = b + lane; j < e; j += 64){
    int eid = eids[j];
    float4 ev = *(const float4*)&ebuf[(size_t)eid*4];
    float4 ex = { expf(ev.x - m.x), expf(ev.y - m.y), expf(ev.z - m.z), expf(ev.w - m.w) };
    *(float4*)&alpha[(size_t)eid*4] = ex;
    s.x += ex.x; s.y += ex.y; s.z += ex.z; s.w += ex.w;
  }
#pragma unroll
  for (int o = 32; o > 0; o >>= 1){
    s.x += __shfl_xor(s.x, o, 64);
    s.y += __shfl_xor(s.y, o, 64);
    s.z += __shfl_xor(s.z, o, 64);
    s.w += __shfl_xor(s.w, o, 64);
  }
  float4 r = { 1.f/s.x, 1.f/s.y, 1.f/s.z, 1.f/s.w };
  for (int j = b + lane; j < e; j += 64){
    int eid = eids[j];
    float4 av = *(const float4*)&alpha[(size_t)eid*4];
    av.x *= r.x; av.y *= r.y; av.z *= r.z; av.w *= r.w;
    *(float4*)&alpha[(size_t)eid*4] = av;
  }
}

// z1[n, h*512+c] = sum_e alpha[e,h] * x[src(e),c], written bf16 hi/lo split
__global__ __launch_bounds__(256) void k_agg1_split(const float* __restrict__ x, const float* __restrict__ alpha,
                      const int* __restrict__ rowptr, const int* __restrict__ eids,
                      const int* __restrict__ ei, unsigned short* __restrict__ z1hi,
                      unsigned short* __restrict__ z1lo){
  int n = blockIdx.x, t = threadIdx.x;
  float2 a0 = {0,0}, a1 = {0,0}, a2 = {0,0}, a3 = {0,0};
  int b = rowptr[n], e = rowptr[n + 1];
  for (int j = b; j < e; ++j){
    int eid = eids[j];
    int s = (eid < Ne) ? ei[eid] : (eid - Ne);
    float4 av = *(const float4*)&alpha[(size_t)eid*4];
    float2 xv = *(const float2*)&x[(size_t)s*512 + t*2];
    a0.x += av.x*xv.x; a0.y += av.x*xv.y;
    a1.x += av.y*xv.x; a1.y += av.y*xv.y;
    a2.x += av.z*xv.x; a2.y += av.z*xv.y;
    a3.x += av.w*xv.x; a3.y += av.w*xv.y;
  }
  size_t base = (size_t)n*2048 + t*2;
  float2 av[4] = {a0, a1, a2, a3};
#pragma unroll
  for (int h = 0; h < 4; h++){
    ushort2 hh, ll;
    split2(av[h].x, hh.x, ll.x);
    split2(av[h].y, hh.y, ll.y);
    *(ushort2*)&z1hi[base + h*512] = hh;
    *(ushort2*)&z1lo[base + h*512] = ll;
  }
}

// x3[n,:] = lrelu( sum_e alpha[e,h]*H[src,:] + b2_h, 0.01 ), fp16 in/out. Block per dst node.
__global__ __launch_bounds__(256) void k_agg2b(const unsigned short* __restrict__ H,
                      const float* __restrict__ alpha,
                      const int* __restrict__ rowptr, const int* __restrict__ eids,
                      const int* __restrict__ ei, unsigned short* __restrict__ x3,
                      const float* __restrict__ b2, int h){
  int n = blockIdx.x, t = threadIdx.x;
  float acc[8] = {0,0,0,0,0,0,0,0};
  int b = rowptr[n], e = rowptr[n + 1];
  for (int j = b; j < e; ++j){
    int eid = eids[j];
    int s = (eid < Ne) ? ei[eid] : (eid - Ne);
    float a = alpha[(size_t)eid*4 + h];
    f16x8 hv = *(const f16x8*)&H[(size_t)s*2048 + t*8];
#pragma unroll
    for (int q = 0; q < 8; q++) acc[q] += a * (float)hv[q];
  }
  const float* bb = b2 + (size_t)h*2048 + t*8;
  ushort4 o0, o1;
  float4 b0 = *(const float4*)bb;
  float4 b1 = *(const float4*)(bb + 4);
  o0.x = f2h(lrelu(acc[0] + b0.x, 0.01f)); o0.y = f2h(lrelu(acc[1] + b0.y, 0.01f));
  o0.z = f2h(lrelu(acc[2] + b0.z, 0.01f)); o0.w = f2h(lrelu(acc[3] + b0.w, 0.01f));
  o1.x = f2h(lrelu(acc[4] + b1.x, 0.01f)); o1.y = f2h(lrelu(acc[5] + b1.y, 0.01f));
  o1.z = f2h(lrelu(acc[6] + b1.z, 0.01f)); o1.w = f2h(lrelu(acc[7] + b1.w, 0.01f));
  size_t base = (size_t)n*2048 + t*8;
  *(ushort4*)&x3[base]     = o0;
  *(ushort4*)&x3[base + 4] = o1;
}

// transpose + split: out[col][k] = split(W[k][coloff+col]); out stride K.
template<bool HALF, bool STORELO>
__global__ __launch_bounds__(256) void k_wsplit(const float* __restrict__ W, int ldw, int coloff, int K,
                       unsigned short* __restrict__ whi, unsigned short* __restrict__ wlo){
  __shared__ float tile[32][33];
  int bk = blockIdx.x * 32, bn = blockIdx.y * 32;
  int tx = threadIdx.x & 31, ty = threadIdx.x >> 5;
#pragma unroll
  for (int i = 0; i < 4; i++){
    int k = bk + ty + i*8;
    tile[ty + i*8][tx] = W[(size_t)k*ldw + coloff + bn + tx];
  }
  __syncthreads();
#pragma unroll
  for (int i = 0; i < 4; i++){
    int n = bn + ty + i*8;
    float v = tile[tx][ty + i*8];
    unsigned short hh, ll;
    if (HALF) split2h(v, hh, ll); else split2(v, hh, ll);
    whi[(size_t)n*K + bk + tx] = hh;
    if (STORELO) wlo[(size_t)n*K + bk + tx] = ll;
  }
}

// ---------------- L2 dense GEMM: r12 = r9 shape, ONE barrier per K-step ----------------
// H[4096][2048] = x2[4096][2048k] x W2h^T[2048n][2048k]; fp16 2-term C = Ah*Bh + Al*Bh.
// BM=128, BN=256, 8 waves, 3-buffer LDS (96KB), counted vmcnt(4), 2-deep prefetch.
// K-step: {4 gloads(kt+2) -> 12 ds_reads(kt) -> setprio + 32 MFMA -> vmcnt(4) ->
// s_barrier -> sched_barrier(0)}. Compiler fine-grains lgkmcnt for ds_read->MFMA.
// Safety: buf(kt+2) last read at kt-1 (consumed before that step's barrier); each
// wave's vmcnt(4) drains its own kt+1 loads before the shared barrier.
__global__ __launch_bounds__(512) void k_gemm256(
    const unsigned short* __restrict__ Ah, const unsigned short* __restrict__ Al,
    const unsigned short* __restrict__ Bh, unsigned short* __restrict__ Cout)
{
  __shared__ __align__(16) unsigned short lds[49152];   // 3 x (A 8192 + B 8192) ushorts
  const int t = threadIdx.x;
  const int bid = blockIdx.y * 8 + blockIdx.x;
  const int sbid = (bid & 7) * 32 + (bid >> 3);
  const int brow = (sbid >> 3) * 128, bcol = (sbid & 7) * 256;
  const int w = t >> 6, lane = t & 63;
  const int wm = (w >> 2) * 64, wn = (w & 3) * 64;
  constexpr int BUF = 16384, BOFF = 8192;   // ushorts

  // A staging: row = i*64+(t>>3), phys chunk t&7, logical = phys^(row&7)
  const int asr = t >> 3;
  const int ascc = (t & 7) ^ (asr & 7);
  const unsigned short* asrc = (ascc < 4 ? Ah : Al) + (size_t)(brow + asr)*2048 + (size_t)(ascc & 3)*8;
  // B staging: row = i*128+(t>>2), phys chunk t&3, logical = phys^((row>>1)&3)
  const int bsr = t >> 2;
  const int bscc = (t & 3) ^ ((bsr >> 1) & 3);
  const unsigned short* bsrc = Bh + (size_t)(bcol + bsr)*2048 + (size_t)bscc*8;
  const int adst = w * 512;           // + buf*BUF + i*4096 (+ lane*16B implicit)
  const int bdst = BOFF + w * 512;

  const int fr = lane & 15, kc = lane >> 4;
  const int aswz = (kc ^ (lane & 7)) * 8;
  const int bswz = (kc ^ ((lane >> 1) & 3)) * 8;
  int aoff[4], boff[4];
#pragma unroll
  for (int m = 0; m < 4; m++) aoff[m] = (wm + m*16 + fr)*64 + aswz;
#pragma unroll
  for (int n = 0; n < 4; n++) boff[n] = BOFF + (wn + n*16 + fr)*32 + bswz;

  f32x4 acc[4][4];
#pragma unroll
  for (int m = 0; m < 4; m++)
#pragma unroll
    for (int n = 0; n < 4; n++) acc[m][n] = f32x4{0.f, 0.f, 0.f, 0.f};

  // prologue: tile 0 fully first, then tile 1; vmcnt(4) = tile 0 landed.
  gload16(asrc,                        &lds[adst]);
  gload16(asrc + (size_t)64*2048,      &lds[4096 + adst]);
  gload16(bsrc,                        &lds[bdst]);
  gload16(bsrc + (size_t)128*2048,     &lds[4096 + bdst]);
  gload16(asrc + 32,                   &lds[BUF + adst]);
  gload16(asrc + (size_t)64*2048 + 32, &lds[BUF + 4096 + adst]);
  gload16(bsrc + 32,                   &lds[BUF + bdst]);
  gload16(bsrc + (size_t)128*2048 + 32,&lds[BUF + 4096 + bdst]);
  asm volatile("s_waitcnt vmcnt(4)" ::: "memory");
  __builtin_amdgcn_s_barrier();
  __builtin_amdgcn_sched_barrier(0);

  for (int kt = 0; kt < 64; ++kt){
    const int bufo = (kt % 3) * BUF;
    const int nbo  = ((kt + 2) % 3) * BUF;
    const size_t nko = (size_t)(kt + 2) * 32;
    const bool pf = (kt + 2) < 64;

    // prefetch tile kt+2 (its buffer's readers finished at step kt-1's barrier)
    if (pf){
      gload16(asrc + nko,                    &lds[nbo + adst]);
      gload16(asrc + (size_t)64*2048 + nko,  &lds[nbo + 4096 + adst]);
      gload16(bsrc + nko,                    &lds[nbo + bdst]);
      gload16(bsrc + (size_t)128*2048 + nko, &lds[nbo + 4096 + bdst]);
    }

    // fragments of tile kt (globally landed at end of step kt-1)
    f16x8 ah[4], al[4], bfr[4];
#pragma unroll
    for (int m = 0; m < 4; m++){
      ah[m] = *(const f16x8*)&lds[bufo + aoff[m]];
      al[m] = *(const f16x8*)&lds[bufo + (aoff[m] ^ 32)];
    }
#pragma unroll
    for (int n = 0; n < 4; n++) bfr[n] = *(const f16x8*)&lds[bufo + boff[n]];

    __builtin_amdgcn_s_setprio(1);
#pragma unroll
    for (int n = 0; n < 4; n++){
#pragma unroll
      for (int m = 0; m < 4; m++) acc[m][n] = __builtin_amdgcn_mfma_f32_16x16x32_f16(ah[m], bfr[n], acc[m][n], 0, 0, 0);
#pragma unroll
      for (int m = 0; m < 4; m++) acc[m][n] = __builtin_amdgcn_mfma_f32_16x16x32_f16(al[m], bfr[n], acc[m][n], 0, 0, 0);
    }
    __builtin_amdgcn_s_setprio(0);

    // own kt+1 loads drained (oldest 4 of 8); barrier makes it global
    if (pf) asm volatile("s_waitcnt vmcnt(4)" ::: "memory");
    else    asm volatile("s_waitcnt vmcnt(0)" ::: "memory");
    __builtin_amdgcn_s_barrier();
    __builtin_amdgcn_sched_barrier(0);
  }

#pragma unroll
  for (int m = 0; m < 4; m++){
    const int row0 = brow + wm + m*16 + kc*4;
#pragma unroll
    for (int n = 0; n < 4; n++){
      const int col = bcol + wn + n*16 + fr;
#pragma unroll
      for (int r = 0; r < 4; r++)
        Cout[(size_t)(row0 + r)*2048 + col] = f2h(acc[m][n][r]);
    }
  }
}

// ---------------- MFMA GEMM (128x128): bf16 3-term, or fp16 exact-A 2-term ----------------
// OUTMODE: 0 = fp32 (+BETA1), 1 = bf16, 2 = fp16 hi/lo split to Cout/Cout2
template<int KLEN, bool EXACTA, bool HALF, int OUTMODE, bool BETA1, bool ACT, bool HASBIAS>
__global__ __launch_bounds__(256) void k_gemm2(
    const unsigned short* __restrict__ Ah, const unsigned short* __restrict__ Al, int lda, size_t az,
    const unsigned short* __restrict__ Bh, const unsigned short* __restrict__ Bl, int ldb, size_t bz,
    void* __restrict__ Cout, void* __restrict__ Cout2, int ldc, size_t cz,
    const float* __restrict__ bias, size_t biasz)
{
  __shared__ unsigned short lds[16384];   // A: [0,8192) ushorts, B: [8192,16384)
  const int t = threadIdx.x;
  const int z = blockIdx.z;
  const int brow = blockIdx.y * 128, bcol = blockIdx.x * 128;
  const int wid = t >> 6, lane = t & 63;
  const int wm = (wid >> 1) * 64, wn = (wid & 1) * 64;

  const int sr = t >> 3, sc = t & 7;
  const int scc = sc ^ (sr & 7);
  const unsigned short* asrc = (scc < 4 ? Ah : Al) + (size_t)(brow + sr)*lda + (size_t)z*az + (size_t)(scc & 3)*8;
  const unsigned short* bsrc = (scc < 4 ? Bh : Bl) + (size_t)(bcol + sr)*ldb + (size_t)z*bz + (size_t)(scc & 3)*8;
  unsigned short* adst = &lds[(size_t)wid * 512];
  unsigned short* bdst = &lds[8192 + (size_t)wid * 512];

  const int fr = lane & 15, kc = lane >> 4;
  const int swz = ((kc ^ (lane & 7)) << 3);
  int aoff[4], boff[4];
#pragma unroll
  for (int m = 0; m < 4; m++) aoff[m] = (wm + m*16 + fr)*64 + swz;
#pragma unroll
  for (int n = 0; n < 4; n++) boff[n] = 8192 + (wn + n*16 + fr)*64 + swz;

  f32x4 acc[4][4];
#pragma unroll
  for (int m = 0; m < 4; m++)
#pragma unroll
    for (int n = 0; n < 4; n++) acc[m][n] = f32x4{0.f, 0.f, 0.f, 0.f};

  for (int kt = 0; kt < KLEN/32; ++kt){
    const size_t ko = (size_t)kt * 32;
#pragma unroll
    for (int i = 0; i < 4; i++){
      gload16(asrc + (size_t)i*32*lda + ko, adst + i*2048);
      gload16(bsrc + (size_t)i*32*ldb + ko, bdst + i*2048);
    }
    __syncthreads();

    if (HALF){
      f16x8 ah[4], bh[4], bl[4];
#pragma unroll
      for (int m = 0; m < 4; m++) ah[m] = *(const f16x8*)&lds[aoff[m]];
#pragma unroll
      for (int n = 0; n < 4; n++){
        bh[n] = *(const f16x8*)&lds[boff[n]];
        bl[n] = *(const f16x8*)&lds[boff[n] ^ 32];
      }
#pragma unroll
      for (int m = 0; m < 4; m++)
#pragma unroll
        for (int n = 0; n < 4; n++){
          acc[m][n] = __builtin_amdgcn_mfma_f32_16x16x32_f16(ah[m], bh[n], acc[m][n], 0, 0, 0);
          acc[m][n] = __builtin_amdgcn_mfma_f32_16x16x32_f16(ah[m], bl[n], acc[m][n], 0, 0, 0);
        }
    } else {
      bf16x8 ah[4], al[4], bh[4], bl[4];
#pragma unroll
      for (int m = 0; m < 4; m++){
        ah[m] = *(const bf16x8*)&lds[aoff[m]];
        if (!EXACTA) al[m] = *(const bf16x8*)&lds[aoff[m] ^ 32];
      }
#pragma unroll
      for (int n = 0; n < 4; n++){
        bh[n] = *(const bf16x8*)&lds[boff[n]];
        bl[n] = *(const bf16x8*)&lds[boff[n] ^ 32];
      }
#pragma unroll
      for (int m = 0; m < 4; m++)
#pragma unroll
        for (int n = 0; n < 4; n++){
          acc[m][n] = __builtin_amdgcn_mfma_f32_16x16x32_bf16(ah[m], bh[n], acc[m][n], 0, 0, 0);
          acc[m][n] = __builtin_amdgcn_mfma_f32_16x16x32_bf16(ah[m], bl[n], acc[m][n], 0, 0, 0);
          if (!EXACTA)
            acc[m][n] = __builtin_amdgcn_mfma_f32_16x16x32_bf16(al[m], bh[n], acc[m][n], 0, 0, 0);
        }
    }
    __syncthreads();
  }

  float bv[4] = {0.f, 0.f, 0.f, 0.f};
  if (HASBIAS){
#pragma unroll
    for (int n = 0; n < 4; n++) bv[n] = bias[(size_t)z*biasz + bcol + wn + n*16 + fr];
  }
  float* Cf = (float*)Cout + (size_t)z*cz;
  unsigned short* Cb = (unsigned short*)Cout + (size_t)z*cz;
  unsigned short* Cl = (unsigned short*)Cout2 + (size_t)z*cz;
#pragma unroll
  for (int m = 0; m < 4; m++){
    const int row0 = brow + wm + m*16 + kc*4;
#pragma unroll
    for (int n = 0; n < 4; n++){
      const int col = bcol + wn + n*16 + fr;
#pragma unroll
      for (int r = 0; r < 4; r++){
        float v = acc[m][n][r] + bv[n];
        if (ACT) v = lrelu(v, 0.01f);
        size_t idx = (size_t)(row0 + r)*ldc + col;
        if (OUTMODE == 0){
          float* cp = &Cf[idx];
          if (BETA1) v += *cp;
          *cp = v;
        } else if (OUTMODE == 1){
          Cb[idx] = f2bf(v);
        } else {
          unsigned short hh, ll; split2h(v, hh, ll);
          Cb[idx] = hh; Cl[idx] = ll;
        }
      }
    }
  }
}

// stage 1: per (slice, graph) partial sums over stride-32 node slices
__global__ void k_gsum(const float* __restrict__ yp, const float* __restrict__ bout,
                       const int* __restrict__ batch, float* __restrict__ part){
  const int s = blockIdx.x, g = blockIdx.y, t = threadIdx.x;
  __shared__ int sb[2];
  if (t < 2){
    int key = g + t, lo = 0, hi = Nn;
    while (lo < hi){ int mid = (lo + hi) >> 1; if (batch[mid] < key) lo = mid + 1; else hi = mid; }
    sb[t] = lo;
  }
  __syncthreads();
  const int b = sb[0], e = sb[1];
  const size_t P = (size_t)Nn * 256;
  float acc = 0.f;
  float bt = bout[t];
  for (int n = b + s; n < e; n += 32){
    size_t i = (size_t)n*256 + t;
    float v = yp[i] + yp[P + i] + yp[2*P + i] + yp[3*P + i] + bt;
    acc += lrelu(v, 0.01f);
  }
  part[(size_t)(g*32 + s)*256 + t] = acc;
}

// stage 2: sum 32 slices, divide by count
__global__ void k_gfin(const float* __restrict__ part, const int* __restrict__ batch,
                       float* __restrict__ out){
  const int g = blockIdx.x, t = threadIdx.x;
  __shared__ int sb[2];
  if (t < 2){
    int key = g + t, lo = 0, hi = Nn;
    while (lo < hi){ int mid = (lo + hi) >> 1; if (batch[mid] < key) lo = mid + 1; else hi = mid; }
    sb[t] = lo;
  }
  __syncthreads();
  const int cnt = sb[1] - sb[0];
  float s = 0.f;
#pragma unroll
  for (int k = 0; k < 32; k++) s += part[(size_t)(g*32 + k)*256 + t];
  out[g*256 + t] = s / fmaxf((float)cnt, 1.f);
}

// ---------------- launch ----------------
extern "C" void kernel_launch(void* const* d_in, const int* in_sizes, int n_in,
                              void* d_out, int out_size, void* d_ws, size_t ws_size,
                              hipStream_t stream){
  const float* xg    = (const float*)d_in[0];
  const float* ac    = (const float*)d_in[1];
  const float* ti    = (const float*)d_in[2];
  const float* eattr = (const float*)d_in[3];
  const int*   ei    = (const int*)  d_in[4];
  const int*   batch = (const int*)  d_in[5];
  const float* W1    = (const float*)d_in[6];
  const float* as1w  = (const float*)d_in[7];
  const float* ad1w  = (const float*)d_in[8];
  const float* ae1w  = (const float*)d_in[9];
  const float* We1   = (const float*)d_in[10];
  const float* b1    = (const float*)d_in[11];
  const float* W2    = (const float*)d_in[12];
  const float* as2w  = (const float*)d_in[13];
  const float* ad2w  = (const float*)d_in[14];
  const float* ae2w  = (const float*)d_in[15];
  const float* We2   = (const float*)d_in[16];
  const float* b2    = (const float*)d_in[17];
  const float* Wout  = (const float*)d_in[18];
  const float* bout  = (const float*)d_in[19];
  float* out = (float*)d_out;
  float* ws  = (float*)d_ws;
  if (ws_size < WS_FLOATS * sizeof(float)) return;
  int* iws = (int*)(ws + OFF_I);

  unsigned short* z1hi = (unsigned short*)(ws + OFF_Z1HI);
  unsigned short* z1lo = (unsigned short*)(ws + OFF_Z1LO);
  unsigned short* wt1h = (unsigned short*)(ws + OFF_WT1H);
  unsigned short* wt1l = (unsigned short*)(ws + OFF_WT1L);
  unsigned short* x2hi = (unsigned short*)(ws + OFF_X2HI);
  unsigned short* x2lo = (unsigned short*)(ws + OFF_X2LO);
  unsigned short* whi  = (unsigned short*)(ws + OFF_X);
  unsigned short* woh  = (unsigned short*)(ws + OFF_WOH);
  unsigned short* wol  = (unsigned short*)(ws + OFF_WOL);
  unsigned short* Hb   = (unsigned short*)(ws + OFF_H);
  unsigned short* x3   = (unsigned short*)(ws + OFF_X3);

  hipMemsetAsync(iws + I_DEG, 0, Nn * sizeof(int), stream);
  k_concat <<<8192, 256, 0, stream>>>(xg, ac, ti, ws + OFF_X);
  k_count  <<<128,  256, 0, stream>>>(ei, iws + I_DEG);
  k_scan   <<<1,   1024, 0, stream>>>(iws + I_DEG, iws + I_RP, iws + I_CUR);
  k_fill   <<<144,  256, 0, stream>>>(ei, iws + I_CUR, iws + I_EID);
  k_sort   <<<64,    64, 0, stream>>>(iws + I_RP, iws + I_EID);
  k_loopattr<<<256, 256, 0, stream>>>(eattr, iws + I_RP, iws + I_EID, ws + OFF_LP);

  k_proj   <<<512,  256, 0, stream>>>(W1, as1w, ad1w, ws + OFF_WS1, ws + OFF_WD1, 512, 512);
  k_proj   <<<2048, 256, 0, stream>>>(W2, as2w, ad2w, ws + OFF_WS2, ws + OFF_WD2, 2048, 2048);
  k_aeproj <<<16,   256, 0, stream>>>(We1, ae1w, ws + OFF_AE1, 512);
  k_aeproj <<<16,   256, 0, stream>>>(We2, ae2w, ws + OFF_AE2, 2048);
  k_wsplit<true, true><<<dim3(256, 8), 256, 0, stream>>>(Wout, 256, 0, 8192, woh, wol);   // fp16 [256][8192]

  // ---- layer 1 (bf16 3-term); epilogue writes x2 as fp16 hi/lo directly ----
  k_asad<false><<<4096, 256, 0, stream>>>(ws + OFF_X, nullptr, ws + OFF_WS1, ws + OFF_WD1, ws + OFF_AS1, ws + OFF_AD1, 512);
  k_edge      <<<144,  256, 0, stream>>>(eattr, ws + OFF_LP, ei, ws + OFF_AS1, ws + OFF_AD1, ws + OFF_AE1, ws + OFF_EB);
  k_softmax   <<<1024, 256, 0, stream>>>(iws + I_RP, iws + I_EID, ws + OFF_EB, ws + OFF_AL);
  k_agg1_split<<<4096, 256, 0, stream>>>(ws + OFF_X, ws + OFF_AL, iws + I_RP, iws + I_EID, ei, z1hi, z1lo);
  // X dead; wt1 overlays it
  k_wsplit<false, true><<<dim3(16, 64), 256, 0, stream>>>(W1, 2048, 0, 512, wt1h, wt1l);  // bf16 [2048][512]
  k_gemm2<512, false, false, 2, false, true, true><<<dim3(4, 32, 4), 256, 0, stream>>>(
      z1hi, z1lo, 2048, 512,  wt1h, wt1l, 512, 512*512,
      x2hi, x2lo, 2048, 512,  b1, 512);

  // ---- layer 2 attention (x2 = hi+lo fp16, reconstructed: near-exact) ----
  k_asad<true><<<4096, 256, 0, stream>>>(x2hi, x2lo, ws + OFF_WS2, ws + OFF_WD2, ws + OFF_AS2, ws + OFF_AD2, 2048);
  k_edge   <<<144,  256, 0, stream>>>(eattr, ws + OFF_LP, ei, ws + OFF_AS2, ws + OFF_AD2, ws + OFF_AE2, ws + OFF_EB);
  k_softmax<<<1024, 256, 0, stream>>>(iws + I_RP, iws + I_EID, ws + OFF_EB, ws + OFF_AL);

  // ---- layer 2 + fc, per head: H = x2@W2_h^T (fp16 MFMA), sparse agg of fp16 H, fp16 FC ----
  for (int h = 0; h < 4; ++h){
    k_wsplit<true, false><<<dim3(64, 64), 256, 0, stream>>>(W2, 8192, h*2048, 2048, whi, nullptr);
    k_gemm256 <<<dim3(8, 32), 512, 0, stream>>>(x2hi, x2lo, whi, Hb);
    k_agg2b   <<<4096, 256, 0, stream>>>(Hb, ws + OFF_AL, iws + I_RP, iws + I_EID, ei, x3, b2, h);
    if (h == 0)
      k_gemm2<512, true, true, 0, false, false, false><<<dim3(2, 32, 4), 256, 0, stream>>>(
          x3, x3, 2048, 512,  woh + (size_t)h*2048, wol + (size_t)h*2048, 8192, 512,
          ws + OFF_YP, nullptr, 256, (size_t)Nn*256,  nullptr, 0);
    else
      k_gemm2<512, true, true, 0, true, false, false><<<dim3(2, 32, 4), 256, 0, stream>>>(
          x3, x3, 2048, 512,  woh + (size_t)h*2048, wol + (size_t)h*2048, 8192, 512,
          ws + OFF_YP, nullptr, 256, (size_t)Nn*256,  nullptr, 0);
  }

  k_gsum<<<dim3(32, 8), 256, 0, stream>>>(ws + OFF_YP, bout, batch, ws + OFF_PART);
  k_gfin<<<8, 256, 0, stream>>>(ws + OFF_PART, batch, out);
}

// Round 14
// 715.932 us; speedup vs baseline: 1.0004x; 1.0004x over previous
//
#include <hip/hip_runtime.h>
#include <math.h>

constexpr int Nn  = 4096;
constexpr int Ne  = 32768;
constexpr int NEf = Ne + Nn;     // real edges + self loops

// ---------------- ws layout (float offsets) ----------------
// R0 [0..2097152)        X fp32 (prep/L1) -> wt1 hi/lo bf16 (L1 gemm) -> whi fp16 [2048][2048] (L2 loop)
// R1 [2097152..10485760) z1 hi/lo bf16 (L1) -> x3 fp16 [4096][2048] (head loop) -> part fp32 (final)
// R2 [10485760..18874368) x2hi/x2lo fp16 [4096][2048] (written by L1 gemm epilogue)
// R3 [18874368..23068672) H fp16 [4096][2048] (L2 loop)
// R5 [25165824..27262976) wtout hi/lo fp16 [256][8192]
// R6 [27262976..31457280) YP 4x [4096][256] fp32
constexpr size_t OFF_X    = 0;
constexpr size_t OFF_WT1H = 0;
constexpr size_t OFF_WT1L = 524288;
constexpr size_t OFF_Z1HI = 2097152;
constexpr size_t OFF_Z1LO = 6291456;
constexpr size_t OFF_X3   = 2097152;     // ushort region (fp16), overlays dead z1
constexpr size_t OFF_PART = 2097152;     // fp32, overlays dead x3 (final)
constexpr size_t OFF_X2HI = 10485760;    // ushort region
constexpr size_t OFF_X2LO = 14680064;    // ushort region
constexpr size_t OFF_H    = 18874368;    // ushort region (fp16) [4096][2048]
constexpr size_t OFF_WOH  = 25165824;    // ushort region [256][8192] fp16
constexpr size_t OFF_WOL  = 26214400;    // ushort region
constexpr size_t OFF_YP   = 27262976;
constexpr size_t OFF_LP  = 31457280;     // [N,16] self-loop edge attr
constexpr size_t OFF_WS1 = OFF_LP  + 65536;   // [512,4]
constexpr size_t OFF_WD1 = OFF_WS1 + 2048;    // [512,4]
constexpr size_t OFF_WS2 = OFF_WD1 + 2048;    // [2048,4]
constexpr size_t OFF_WD2 = OFF_WS2 + 8192;    // [2048,4]
constexpr size_t OFF_AE1 = OFF_WD2 + 8192;    // [16,4]
constexpr size_t OFF_AE2 = OFF_AE1 + 64;      // [16,4]
constexpr size_t OFF_AS1 = OFF_AE2 + 64;      // [N,4]
constexpr size_t OFF_AD1 = OFF_AS1 + 16384;
constexpr size_t OFF_AS2 = OFF_AD1 + 16384;
constexpr size_t OFF_AD2 = OFF_AS2 + 16384;
constexpr size_t OFF_EB  = OFF_AD2 + 16384;          // [Ef,4] logits
constexpr size_t OFF_AL  = OFF_EB  + (size_t)NEf*4;  // [Ef,4] alpha
constexpr size_t OFF_I   = OFF_AL  + (size_t)NEf*4;  // int region
constexpr size_t I_DEG = 0;       // [N]
constexpr size_t I_RP  = 4096;    // [N+1] (+pad)
constexpr size_t I_CUR = 8200;    // [N]
constexpr size_t I_EID = 12296;   // [Ef]
constexpr size_t WS_FLOATS = OFF_I + I_EID + (size_t)NEf + 64;

using bf16x8 = __bf16 __attribute__((ext_vector_type(8)));
using f16x8  = _Float16 __attribute__((ext_vector_type(8)));
using f32x4  = float __attribute__((ext_vector_type(4)));

__device__ __forceinline__ float wred64(float v){
#pragma unroll
  for (int o = 32; o > 0; o >>= 1) v += __shfl_down(v, o, 64);
  return v;
}
__device__ __forceinline__ float lrelu(float v, float s){ return v > 0.f ? v : s * v; }

__device__ __forceinline__ unsigned short f2bf(float x){  // RTNE
  unsigned int u = __float_as_uint(x);
  unsigned int r = (u + 0x7FFFu + ((u >> 16) & 1u)) >> 16;
  return (unsigned short)r;
}
__device__ __forceinline__ float bf2f(unsigned short h){
  return __uint_as_float((unsigned int)h << 16);
}
__device__ __forceinline__ void split2(float x, unsigned short& h, unsigned short& l){
  h = f2bf(x);
  l = f2bf(x - bf2f(h));
}
__device__ __forceinline__ unsigned short f2h(float x){
  _Float16 h = (_Float16)x;
  return __builtin_bit_cast(unsigned short, h);
}
__device__ __forceinline__ float h2f(unsigned short u){
  return (float)__builtin_bit_cast(_Float16, u);
}
__device__ __forceinline__ void split2h(float x, unsigned short& h, unsigned short& l){
  _Float16 hh = (_Float16)x;
  h = __builtin_bit_cast(unsigned short, hh);
  _Float16 ll = (_Float16)(x - (float)hh);
  l = __builtin_bit_cast(unsigned short, ll);
}
__device__ __forceinline__ void gload16(const void* g, void* l){
  __builtin_amdgcn_global_load_lds((const __attribute__((address_space(1))) void*)g,
                                   (__attribute__((address_space(3))) void*)l, 16, 0, 0);
}

// ---------------- small prep kernels ----------------
__global__ void k_concat(const float* __restrict__ xg, const float* __restrict__ ac,
                         const float* __restrict__ ti, float* __restrict__ x){
  int i = blockIdx.x * 256 + threadIdx.x;          // over N*512
  int n = i >> 9, c = i & 511;
  float v;
  if (c < 256)      v = xg[(size_t)n*256 + c];
  else if (c < 384) v = ac[(size_t)n*128 + (c-256)];
  else              v = ti[(size_t)n*128 + (c-384)];
  x[i] = v;
}

__global__ void k_count(const int* __restrict__ ei, int* __restrict__ deg){
  int e = blockIdx.x * 256 + threadIdx.x;
  if (e < Ne) atomicAdd(&deg[ei[Ne + e]], 1);
}

__global__ void k_scan(const int* __restrict__ deg, int* __restrict__ rowptr, int* __restrict__ cursor){
  __shared__ int sd[1024];
  int t = threadIdx.x;
  int v[4]; int s = 0;
#pragma unroll
  for (int i = 0; i < 4; i++){ v[i] = s; s += deg[t*4 + i] + 1; }   // +1 self loop
  sd[t] = s;
  __syncthreads();
  for (int off = 1; off < 1024; off <<= 1){
    int x = (t >= off) ? sd[t - off] : 0;
    __syncthreads();
    sd[t] += x;
    __syncthreads();
  }
  int base = (t == 0) ? 0 : sd[t - 1];
#pragma unroll
  for (int i = 0; i < 4; i++){ int rp = base + v[i]; rowptr[t*4 + i] = rp; cursor[t*4 + i] = rp; }
  if (t == 1023) rowptr[4096] = sd[1023];
}

__global__ void k_fill(const int* __restrict__ ei, int* __restrict__ cursor, int* __restrict__ eids){
  int e = blockIdx.x * 256 + threadIdx.x;
  if (e >= NEf) return;
  int d = (e < Ne) ? ei[Ne + e] : (e - Ne);
  int p = atomicAdd(&cursor[d], 1);
  eids[p] = e;
}

__global__ void k_sort(const int* __restrict__ rowptr, int* __restrict__ eids){
  int n = blockIdx.x * 64 + threadIdx.x;
  if (n >= Nn) return;
  int b = rowptr[n], e = rowptr[n + 1];
  for (int i = b + 1; i < e; i++){
    int key = eids[i]; int j = i - 1;
    while (j >= b && eids[j] > key){ eids[j+1] = eids[j]; j--; }
    eids[j+1] = key;
  }
}

__global__ void k_loopattr(const float* __restrict__ eattr, const int* __restrict__ rowptr,
                           const int* __restrict__ eids, float* __restrict__ lp){
  int idx = blockIdx.x * 256 + threadIdx.x;        // N*16
  int n = idx >> 4, a = idx & 15;
  if (n >= Nn) return;
  int b = rowptr[n], e = rowptr[n + 1];
  float s = 0.f; int cnt = 0;
  for (int j = b; j < e; ++j){
    int id = eids[j];
    if (id < Ne){ s += eattr[(size_t)id*16 + a]; cnt++; }
  }
  lp[(size_t)n*16 + a] = s / fmaxf((float)cnt, 1.f);
}

// Ws[k,h] = sum_c W[k, h*C+c]*a_s[h,c] ; Wd likewise.
__global__ void k_proj(const float* __restrict__ W, const float* __restrict__ a_s,
                       const float* __restrict__ a_d, float* __restrict__ Ws,
                       float* __restrict__ Wd, int K, int C){
  int gid = blockIdx.x * 256 + threadIdx.x;
  int wave = gid >> 6, lane = gid & 63;
  int h = wave & 3, k = wave >> 2;
  if (k >= K) return;
  const float* wrow = W + (size_t)k * (4*C) + (size_t)h * C;
  const float* ar = a_s + (size_t)h * C;
  const float* dr = a_d + (size_t)h * C;
  float ps = 0.f, pd = 0.f;
  for (int c = lane; c < C; c += 64){ float w = wrow[c]; ps += w * ar[c]; pd += w * dr[c]; }
  ps = wred64(ps); pd = wred64(pd);
  if (lane == 0){ Ws[k*4 + h] = ps; Wd[k*4 + h] = pd; }
}

// one wave per (k,h): outp[k*4+h] = dot(We[k, h*C:(h+1)*C], ae[h,:])
__global__ void k_aeproj(const float* __restrict__ We, const float* __restrict__ ae,
                         float* __restrict__ outp, int C){
  int gid = blockIdx.x * 256 + threadIdx.x;
  int wave = gid >> 6, lane = gid & 63;
  int h = wave & 3, k = wave >> 2;
  if (k >= 16) return;
  const float* wrow = We + (size_t)k * (4*C) + (size_t)h * C;
  const float* ar = ae + (size_t)h * C;
  float s = 0.f;
  for (int c = lane; c < C; c += 64) s += wrow[c] * ar[c];
  s = wred64(s);
  if (lane == 0) outp[k*4 + h] = s;
}

// as[n,h], ad[n,h] = x[n,:] @ Ws/Wd. Block per node.
// HALF: x given as fp16 hi/lo pair (reconstructed hi+lo, near-exact).
template<bool HALF>
__global__ __launch_bounds__(256) void k_asad(const void* __restrict__ xp, const void* __restrict__ xlp,
                      const float* __restrict__ Ws,
                      const float* __restrict__ Wd, float* __restrict__ as_,
                      float* __restrict__ ad_, int D){
  int n = blockIdx.x, t = threadIdx.x;
  float p[8] = {0,0,0,0,0,0,0,0};
  if (HALF){
    const unsigned short* rh = (const unsigned short*)xp + (size_t)n * D;
    const unsigned short* rl = (const unsigned short*)xlp + (size_t)n * D;
    for (int c = t; c < D; c += 256){
      float xv = h2f(rh[c]) + h2f(rl[c]);
      float4 ws4 = *(const float4*)&Ws[c*4];
      float4 wd4 = *(const float4*)&Wd[c*4];
      p[0] += xv * ws4.x; p[1] += xv * ws4.y; p[2] += xv * ws4.z; p[3] += xv * ws4.w;
      p[4] += xv * wd4.x; p[5] += xv * wd4.y; p[6] += xv * wd4.z; p[7] += xv * wd4.w;
    }
  } else {
    const float* row = (const float*)xp + (size_t)n * D;
    for (int c = t; c < D; c += 256){
      float xv = row[c];
      float4 ws4 = *(const float4*)&Ws[c*4];
      float4 wd4 = *(const float4*)&Wd[c*4];
      p[0] += xv * ws4.x; p[1] += xv * ws4.y; p[2] += xv * ws4.z; p[3] += xv * ws4.w;
      p[4] += xv * wd4.x; p[5] += xv * wd4.y; p[6] += xv * wd4.z; p[7] += xv * wd4.w;
    }
  }
  __shared__ float sm[4][8];
  int lane = t & 63, wid = t >> 6;
#pragma unroll
  for (int q = 0; q < 8; q++){
    float v = wred64(p[q]);
    if (lane == 0) sm[wid][q] = v;
  }
  __syncthreads();
  if (t < 8){
    float s = sm[0][t] + sm[1][t] + sm[2][t] + sm[3][t];
    if (t < 4) as_[(size_t)n*4 + t] = s;
    else       ad_[(size_t)n*4 + (t-4)] = s;
  }
}

__global__ void k_edge(const float* __restrict__ eattr, const float* __restrict__ lp,
                       const int* __restrict__ ei, const float* __restrict__ as_,
                       const float* __restrict__ ad_, const float* __restrict__ aep,
                       float* __restrict__ ebuf){
  int e = blockIdx.x * 256 + threadIdx.x;
  if (e >= NEf) return;
  int s, d; const float* ea;
  if (e < Ne){ s = ei[e]; d = ei[Ne + e]; ea = eattr + (size_t)e * 16; }
  else { s = e - Ne; d = e - Ne; ea = lp + (size_t)(e - Ne) * 16; }
  float eav[16];
#pragma unroll
  for (int k = 0; k < 16; k++) eav[k] = ea[k];
#pragma unroll
  for (int h = 0; h < 4; h++){
    float v = as_[(size_t)s*4 + h] + ad_[(size_t)d*4 + h];
#pragma unroll
    for (int k = 0; k < 16; k++) v += eav[k] * aep[k*4 + h];
    ebuf[(size_t)e*4 + h] = lrelu(v, 0.2f);
  }
}

// wave-per-node softmax: 4 waves/block, 1024 blocks.
__global__ __launch_bounds__(256) void k_softmax(const int* __restrict__ rowptr, const int* __restrict__ eids,
                          const float* __restrict__ ebuf, float* __restrict__ alpha){
  const int wid = threadIdx.x >> 6, lane = threadIdx.x & 63;
  const int n = blockIdx.x * 4 + wid;
  const int b = rowptr[n], e = rowptr[n + 1];
  float4 m = {-1e30f, -1e30f, -1e30f, -1e30f};
  for (int j = b + lane; j < e; j += 64){
    float4 ev = *(const float4*)&ebuf[(size_t)eids[j]*4];
    m.x = fmaxf(m.x, ev.x); m.y = fmaxf(m.y, ev.y);
    m.z = fmaxf(m.z, ev.z); m.w = fmaxf(m.w, ev.w);
  }
#pragma unroll
  for (int o = 32; o > 0; o >>= 1){
    m.x = fmaxf(m.x, __shfl_xor(m.x, o, 64));
    m.y = fmaxf(m.y, __shfl_xor(m.y, o, 64));
    m.z = fmaxf(m.z, __shfl_xor(m.z, o, 64));
    m.w = fmaxf(m.w, __shfl_xor(m.w, o, 64));
  }
  float4 s = {0.f, 0.f, 0.f, 0.f};
  for (int j = b + lane; j < e; j += 64){
    int eid = eids[j];
    float4 ev = *(const float4*)&ebuf[(size_t)eid*4];
    float4 ex = { expf(ev.x - m.x), expf(ev.y - m.y), expf(ev.z - m.z), expf(ev.w - m.w) };
    *(float4*)&alpha[(size_t)eid*4] = ex;
    s.x += ex.x; s.y += ex.y; s.z += ex.z; s.w += ex.w;
  }
#pragma unroll
  for (int o = 32; o > 0; o >>= 1){
    s.x += __shfl_xor(s.x, o, 64);
    s.y += __shfl_xor(s.y, o, 64);
    s.z += __shfl_xor(s.z, o, 64);
    s.w += __shfl_xor(s.w, o, 64);
  }
  float4 r = { 1.f/s.x, 1.f/s.y, 1.f/s.z, 1.f/s.w };
  for (int j = b + lane; j < e; j += 64){
    int eid = eids[j];
    float4 av = *(const float4*)&alpha[(size_t)eid*4];
    av.x *= r.x; av.y *= r.y; av.z *= r.z; av.w *= r.w;
    *(float4*)&alpha[(size_t)eid*4] = av;
  }
}

// z1[n, h*512+c] = sum_e alpha[e,h] * x[src(e),c], written bf16 hi/lo split
__global__ __launch_bounds__(256) void k_agg1_split(const float* __restrict__ x, const float* __restrict__ alpha,
                      const int* __restrict__ rowptr, const int* __restrict__ eids,
                      const int* __restrict__ ei, unsigned short* __restrict__ z1hi,
                      unsigned short* __restrict__ z1lo){
  int n = blockIdx.x, t = threadIdx.x;
  float2 a0 = {0,0}, a1 = {0,0}, a2 = {0,0}, a3 = {0,0};
  int b = rowptr[n], e = rowptr[n + 1];
  for (int j = b; j < e; ++j){
    int eid = eids[j];
    int s = (eid < Ne) ? ei[eid] : (eid - Ne);
    float4 av = *(const float4*)&alpha[(size_t)eid*4];
    float2 xv = *(const float2*)&x[(size_t)s*512 + t*2];
    a0.x += av.x*xv.x; a0.y += av.x*xv.y;
    a1.x += av.y*xv.x; a1.y += av.y*xv.y;
    a2.x += av.z*xv.x; a2.y += av.z*xv.y;
    a3.x += av.w*xv.x; a3.y += av.w*xv.y;
  }
  size_t base = (size_t)n*2048 + t*2;
  float2 av[4] = {a0, a1, a2, a3};
#pragma unroll
  for (int h = 0; h < 4; h++){
    ushort2 hh, ll;
    split2(av[h].x, hh.x, ll.x);
    split2(av[h].y, hh.y, ll.y);
    *(ushort2*)&z1hi[base + h*512] = hh;
    *(ushort2*)&z1lo[base + h*512] = ll;
  }
}

// x3[n,:] = lrelu( sum_e alpha[e,h]*H[src,:] + b2_h, 0.01 ), fp16 in/out. Block per dst node.
__global__ __launch_bounds__(256) void k_agg2b(const unsigned short* __restrict__ H,
                      const float* __restrict__ alpha,
                      const int* __restrict__ rowptr, const int* __restrict__ eids,
                      const int* __restrict__ ei, unsigned short* __restrict__ x3,
                      const float* __restrict__ b2, int h){
  int n = blockIdx.x, t = threadIdx.x;
  float acc[8] = {0,0,0,0,0,0,0,0};
  int b = rowptr[n], e = rowptr[n + 1];
  for (int j = b; j < e; ++j){
    int eid = eids[j];
    int s = (eid < Ne) ? ei[eid] : (eid - Ne);
    float a = alpha[(size_t)eid*4 + h];
    f16x8 hv = *(const f16x8*)&H[(size_t)s*2048 + t*8];
#pragma unroll
    for (int q = 0; q < 8; q++) acc[q] += a * (float)hv[q];
  }
  const float* bb = b2 + (size_t)h*2048 + t*8;
  ushort4 o0, o1;
  float4 b0 = *(const float4*)bb;
  float4 b1 = *(const float4*)(bb + 4);
  o0.x = f2h(lrelu(acc[0] + b0.x, 0.01f)); o0.y = f2h(lrelu(acc[1] + b0.y, 0.01f));
  o0.z = f2h(lrelu(acc[2] + b0.z, 0.01f)); o0.w = f2h(lrelu(acc[3] + b0.w, 0.01f));
  o1.x = f2h(lrelu(acc[4] + b1.x, 0.01f)); o1.y = f2h(lrelu(acc[5] + b1.y, 0.01f));
  o1.z = f2h(lrelu(acc[6] + b1.z, 0.01f)); o1.w = f2h(lrelu(acc[7] + b1.w, 0.01f));
  size_t base = (size_t)n*2048 + t*8;
  *(ushort4*)&x3[base]     = o0;
  *(ushort4*)&x3[base + 4] = o1;
}

// transpose + split: out[col][k] = split(W[k][coloff+col]); out stride K.
template<bool HALF, bool STORELO>
__global__ __launch_bounds__(256) void k_wsplit(const float* __restrict__ W, int ldw, int coloff, int K,
                       unsigned short* __restrict__ whi, unsigned short* __restrict__ wlo){
  __shared__ float tile[32][33];
  int bk = blockIdx.x * 32, bn = blockIdx.y * 32;
  int tx = threadIdx.x & 31, ty = threadIdx.x >> 5;
#pragma unroll
  for (int i = 0; i < 4; i++){
    int k = bk + ty + i*8;
    tile[ty + i*8][tx] = W[(size_t)k*ldw + coloff + bn + tx];
  }
  __syncthreads();
#pragma unroll
  for (int i = 0; i < 4; i++){
    int n = bn + ty + i*8;
    float v = tile[tx][ty + i*8];
    unsigned short hh, ll;
    if (HALF) split2h(v, hh, ll); else split2(v, hh, ll);
    whi[(size_t)n*K + bk + tx] = hh;
    if (STORELO) wlo[(size_t)n*K + bk + tx] = ll;
  }
}

// ---------------- L2 dense GEMM: r12 = r9 shape, ONE barrier per K-step ----------------
// H[4096][2048] = x2[4096][2048k] x W2h^T[2048n][2048k]; fp16 2-term C = Ah*Bh + Al*Bh.
// BM=128, BN=256, 8 waves, 3-buffer LDS (96KB), counted vmcnt(4), 2-deep prefetch.
// K-step: {4 gloads(kt+2) -> 12 ds_reads(kt) -> setprio + 32 MFMA -> vmcnt(4) ->
// s_barrier -> sched_barrier(0)}. Compiler fine-grains lgkmcnt for ds_read->MFMA.
// Safety: buf(kt+2) last read at kt-1 (consumed before that step's barrier); each
// wave's vmcnt(4) drains its own kt+1 loads before the shared barrier.
__global__ __launch_bounds__(512) void k_gemm256(
    const unsigned short* __restrict__ Ah, const unsigned short* __restrict__ Al,
    const unsigned short* __restrict__ Bh, unsigned short* __restrict__ Cout)
{
  __shared__ __align__(16) unsigned short lds[49152];   // 3 x (A 8192 + B 8192) ushorts
  const int t = threadIdx.x;
  const int bid = blockIdx.y * 8 + blockIdx.x;
  const int sbid = (bid & 7) * 32 + (bid >> 3);
  const int brow = (sbid >> 3) * 128, bcol = (sbid & 7) * 256;
  const int w = t >> 6, lane = t & 63;
  const int wm = (w >> 2) * 64, wn = (w & 3) * 64;
  constexpr int BUF = 16384, BOFF = 8192;   // ushorts

  // A staging: row = i*64+(t>>3), phys chunk t&7, logical = phys^(row&7)
  const int asr = t >> 3;
  const int ascc = (t & 7) ^ (asr & 7);
  const unsigned short* asrc = (ascc < 4 ? Ah : Al) + (size_t)(brow + asr)*2048 + (size_t)(ascc & 3)*8;
  // B staging: row = i*128+(t>>2), phys chunk t&3, logical = phys^((row>>1)&3)
  const int bsr = t >> 2;
  const int bscc = (t & 3) ^ ((bsr >> 1) & 3);
  const unsigned short* bsrc = Bh + (size_t)(bcol + bsr)*2048 + (size_t)bscc*8;
  const int adst = w * 512;           // + buf*BUF + i*4096 (+ lane*16B implicit)
  const int bdst = BOFF + w * 512;

  const int fr = lane & 15, kc = lane >> 4;
  const int aswz = (kc ^ (lane & 7)) * 8;
  const int bswz = (kc ^ ((lane >> 1) & 3)) * 8;
  int aoff[4], boff[4];
#pragma unroll
  for (int m = 0; m < 4; m++) aoff[m] = (wm + m*16 + fr)*64 + aswz;
#pragma unroll
  for (int n = 0; n < 4; n++) boff[n] = BOFF + (wn + n*16 + fr)*32 + bswz;

  f32x4 acc[4][4];
#pragma unroll
  for (int m = 0; m < 4; m++)
#pragma unroll
    for (int n = 0; n < 4; n++) acc[m][n] = f32x4{0.f, 0.f, 0.f, 0.f};

  // prologue: tile 0 fully first, then tile 1; vmcnt(4) = tile 0 landed.
  gload16(asrc,                        &lds[adst]);
  gload16(asrc + (size_t)64*2048,      &lds[4096 + adst]);
  gload16(bsrc,                        &lds[bdst]);
  gload16(bsrc + (size_t)128*2048,     &lds[4096 + bdst]);
  gload16(asrc + 32,                   &lds[BUF + adst]);
  gload16(asrc + (size_t)64*2048 + 32, &lds[BUF + 4096 + adst]);
  gload16(bsrc + 32,                   &lds[BUF + bdst]);
  gload16(bsrc + (size_t)128*2048 + 32,&lds[BUF + 4096 + bdst]);
  asm volatile("s_waitcnt vmcnt(4)" ::: "memory");
  __builtin_amdgcn_s_barrier();
  __builtin_amdgcn_sched_barrier(0);

  for (int kt = 0; kt < 64; ++kt){
    const int bufo = (kt % 3) * BUF;
    const int nbo  = ((kt + 2) % 3) * BUF;
    const size_t nko = (size_t)(kt + 2) * 32;
    const bool pf = (kt + 2) < 64;

    // prefetch tile kt+2 (its buffer's readers finished at step kt-1's barrier)
    if (pf){
      gload16(asrc + nko,                    &lds[nbo + adst]);
      gload16(asrc + (size_t)64*2048 + nko,  &lds[nbo + 4096 + adst]);
      gload16(bsrc + nko,                    &lds[nbo + bdst]);
      gload16(bsrc + (size_t)128*2048 + nko, &lds[nbo + 4096 + bdst]);
    }

    // fragments of tile kt (globally landed at end of step kt-1)
    f16x8 ah[4], al[4], bfr[4];
#pragma unroll
    for (int m = 0; m < 4; m++){
      ah[m] = *(const f16x8*)&lds[bufo + aoff[m]];
      al[m] = *(const f16x8*)&lds[bufo + (aoff[m] ^ 32)];
    }
#pragma unroll
    for (int n = 0; n < 4; n++) bfr[n] = *(const f16x8*)&lds[bufo + boff[n]];

    __builtin_amdgcn_s_setprio(1);
#pragma unroll
    for (int n = 0; n < 4; n++){
#pragma unroll
      for (int m = 0; m < 4; m++) acc[m][n] = __builtin_amdgcn_mfma_f32_16x16x32_f16(ah[m], bfr[n], acc[m][n], 0, 0, 0);
#pragma unroll
      for (int m = 0; m < 4; m++) acc[m][n] = __builtin_amdgcn_mfma_f32_16x16x32_f16(al[m], bfr[n], acc[m][n], 0, 0, 0);
    }
    __builtin_amdgcn_s_setprio(0);

    // own kt+1 loads drained (oldest 4 of 8); barrier makes it global
    if (pf) asm volatile("s_waitcnt vmcnt(4)" ::: "memory");
    else    asm volatile("s_waitcnt vmcnt(0)" ::: "memory");
    __builtin_amdgcn_s_barrier();
    __builtin_amdgcn_sched_barrier(0);
  }

#pragma unroll
  for (int m = 0; m < 4; m++){
    const int row0 = brow + wm + m*16 + kc*4;
#pragma unroll
    for (int n = 0; n < 4; n++){
      const int col = bcol + wn + n*16 + fr;
#pragma unroll
      for (int r = 0; r < 4; r++)
        Cout[(size_t)(row0 + r)*2048 + col] = f2h(acc[m][n][r]);
    }
  }
}

// ---------------- MFMA GEMM (128x128): bf16 3-term, or fp16 exact-A 2-term ----------------
// OUTMODE: 0 = fp32 (+BETA1), 1 = bf16, 2 = fp16 hi/lo split to Cout/Cout2
template<int KLEN, bool EXACTA, bool HALF, int OUTMODE, bool BETA1, bool ACT, bool HASBIAS>
__global__ __launch_bounds__(256) void k_gemm2(
    const unsigned short* __restrict__ Ah, const unsigned short* __restrict__ Al, int lda, size_t az,
    const unsigned short* __restrict__ Bh, const unsigned short* __restrict__ Bl, int ldb, size_t bz,
    void* __restrict__ Cout, void* __restrict__ Cout2, int ldc, size_t cz,
    const float* __restrict__ bias, size_t biasz)
{
  __shared__ unsigned short lds[16384];   // A: [0,8192) ushorts, B: [8192,16384)
  const int t = threadIdx.x;
  const int z = blockIdx.z;
  const int brow = blockIdx.y * 128, bcol = blockIdx.x * 128;
  const int wid = t >> 6, lane = t & 63;
  const int wm = (wid >> 1) * 64, wn = (wid & 1) * 64;

  const int sr = t >> 3, sc = t & 7;
  const int scc = sc ^ (sr & 7);
  const unsigned short* asrc = (scc < 4 ? Ah : Al) + (size_t)(brow + sr)*lda + (size_t)z*az + (size_t)(scc & 3)*8;
  const unsigned short* bsrc = (scc < 4 ? Bh : Bl) + (size_t)(bcol + sr)*ldb + (size_t)z*bz + (size_t)(scc & 3)*8;
  unsigned short* adst = &lds[(size_t)wid * 512];
  unsigned short* bdst = &lds[8192 + (size_t)wid * 512];

  const int fr = lane & 15, kc = lane >> 4;
  const int swz = ((kc ^ (lane & 7)) << 3);
  int aoff[4], boff[4];
#pragma unroll
  for (int m = 0; m < 4; m++) aoff[m] = (wm + m*16 + fr)*64 + swz;
#pragma unroll
  for (int n = 0; n < 4; n++) boff[n] = 8192 + (wn + n*16 + fr)*64 + swz;

  f32x4 acc[4][4];
#pragma unroll
  for (int m = 0; m < 4; m++)
#pragma unroll
    for (int n = 0; n < 4; n++) acc[m][n] = f32x4{0.f, 0.f, 0.f, 0.f};

  for (int kt = 0; kt < KLEN/32; ++kt){
    const size_t ko = (size_t)kt * 32;
#pragma unroll
    for (int i = 0; i < 4; i++){
      gload16(asrc + (size_t)i*32*lda + ko, adst + i*2048);
      gload16(bsrc + (size_t)i*32*ldb + ko, bdst + i*2048);
    }
    __syncthreads();

    if (HALF){
      f16x8 ah[4], bh[4], bl[4];
#pragma unroll
      for (int m = 0; m < 4; m++) ah[m] = *(const f16x8*)&lds[aoff[m]];
#pragma unroll
      for (int n = 0; n < 4; n++){
        bh[n] = *(const f16x8*)&lds[boff[n]];
        bl[n] = *(const f16x8*)&lds[boff[n] ^ 32];
      }
#pragma unroll
      for (int m = 0; m < 4; m++)
#pragma unroll
        for (int n = 0; n < 4; n++){
          acc[m][n] = __builtin_amdgcn_mfma_f32_16x16x32_f16(ah[m], bh[n], acc[m][n], 0, 0, 0);
          acc[m][n] = __builtin_amdgcn_mfma_f32_16x16x32_f16(ah[m], bl[n], acc[m][n], 0, 0, 0);
        }
    } else {
      bf16x8 ah[4], al[4], bh[4], bl[4];
#pragma unroll
      for (int m = 0; m < 4; m++){
        ah[m] = *(const bf16x8*)&lds[aoff[m]];
        if (!EXACTA) al[m] = *(const bf16x8*)&lds[aoff[m] ^ 32];
      }
#pragma unroll
      for (int n = 0; n < 4; n++){
        bh[n] = *(const bf16x8*)&lds[boff[n]];
        bl[n] = *(const bf16x8*)&lds[boff[n] ^ 32];
      }
#pragma unroll
      for (int m = 0; m < 4; m++)
#pragma unroll
        for (int n = 0; n < 4; n++){
          acc[m][n] = __builtin_amdgcn_mfma_f32_16x16x32_bf16(ah[m], bh[n], acc[m][n], 0, 0, 0);
          acc[m][n] = __builtin_amdgcn_mfma_f32_16x16x32_bf16(ah[m], bl[n], acc[m][n], 0, 0, 0);
          if (!EXACTA)
            acc[m][n] = __builtin_amdgcn_mfma_f32_16x16x32_bf16(al[m], bh[n], acc[m][n], 0, 0, 0);
        }
    }
    __syncthreads();
  }

  float bv[4] = {0.f, 0.f, 0.f, 0.f};
  if (HASBIAS){
#pragma unroll
    for (int n = 0; n < 4; n++) bv[n] = bias[(size_t)z*biasz + bcol + wn + n*16 + fr];
  }
  float* Cf = (float*)Cout + (size_t)z*cz;
  unsigned short* Cb = (unsigned short*)Cout + (size_t)z*cz;
  unsigned short* Cl = (unsigned short*)Cout2 + (size_t)z*cz;
#pragma unroll
  for (int m = 0; m < 4; m++){
    const int row0 = brow + wm + m*16 + kc*4;
#pragma unroll
    for (int n = 0; n < 4; n++){
      const int col = bcol + wn + n*16 + fr;
#pragma unroll
      for (int r = 0; r < 4; r++){
        float v = acc[m][n][r] + bv[n];
        if (ACT) v = lrelu(v, 0.01f);
        size_t idx = (size_t)(row0 + r)*ldc + col;
        if (OUTMODE == 0){
          float* cp = &Cf[idx];
          if (BETA1) v += *cp;
          *cp = v;
        } else if (OUTMODE == 1){
          Cb[idx] = f2bf(v);
        } else {
          unsigned short hh, ll; split2h(v, hh, ll);
          Cb[idx] = hh; Cl[idx] = ll;
        }
      }
    }
  }
}

// stage 1: per (slice, graph) partial sums over stride-32 node slices
__global__ void k_gsum(const float* __restrict__ yp, const float* __restrict__ bout,
                       const int* __restrict__ batch, float* __restrict__ part){
  const int s = blockIdx.x, g = blockIdx.y, t = threadIdx.x;
  __shared__ int sb[2];
  if (t < 2){
    int key = g + t, lo = 0, hi = Nn;
    while (lo < hi){ int mid = (lo + hi) >> 1; if (batch[mid] < key) lo = mid + 1; else hi = mid; }
    sb[t] = lo;
  }
  __syncthreads();
  const int b = sb[0], e = sb[1];
  const size_t P = (size_t)Nn * 256;
  float acc = 0.f;
  float bt = bout[t];
  for (int n = b + s; n < e; n += 32){
    size_t i = (size_t)n*256 + t;
    float v = yp[i] + yp[P + i] + yp[2*P + i] + yp[3*P + i] + bt;
    acc += lrelu(v, 0.01f);
  }
  part[(size_t)(g*32 + s)*256 + t] = acc;
}

// stage 2: sum 32 slices, divide by count
__global__ void k_gfin(const float* __restrict__ part, const int* __restrict__ batch,
                       float* __restrict__ out){
  const int g = blockIdx.x, t = threadIdx.x;
  __shared__ int sb[2];
  if (t < 2){
    int key = g + t, lo = 0, hi = Nn;
    while (lo < hi){ int mid = (lo + hi) >> 1; if (batch[mid] < key) lo = mid + 1; else hi = mid; }
    sb[t] = lo;
  }
  __syncthreads();
  const int cnt = sb[1] - sb[0];
  float s = 0.f;
#pragma unroll
  for (int k = 0; k < 32; k++) s += part[(size_t)(g*32 + k)*256 + t];
  out[g*256 + t] = s / fmaxf((float)cnt, 1.f);
}

// ---------------- launch ----------------
extern "C" void kernel_launch(void* const* d_in, const int* in_sizes, int n_in,
                              void* d_out, int out_size, void* d_ws, size_t ws_size,
                              hipStream_t stream){
  const float* xg    = (const float*)d_in[0];
  const float* ac    = (const float*)d_in[1];
  const float* ti    = (const float*)d_in[2];
  const float* eattr = (const float*)d_in[3];
  const int*   ei    = (const int*)  d_in[4];
  const int*   batch = (const int*)  d_in[5];
  const float* W1    = (const float*)d_in[6];
  const float* as1w  = (const float*)d_in[7];
  const float* ad1w  = (const float*)d_in[8];
  const float* ae1w  = (const float*)d_in[9];
  const float* We1   = (const float*)d_in[10];
  const float* b1    = (const float*)d_in[11];
  const float* W2    = (const float*)d_in[12];
  const float* as2w  = (const float*)d_in[13];
  const float* ad2w  = (const float*)d_in[14];
  const float* ae2w  = (const float*)d_in[15];
  const float* We2   = (const float*)d_in[16];
  const float* b2    = (const float*)d_in[17];
  const float* Wout  = (const float*)d_in[18];
  const float* bout  = (const float*)d_in[19];
  float* out = (float*)d_out;
  float* ws  = (float*)d_ws;
  if (ws_size < WS_FLOATS * sizeof(float)) return;
  int* iws = (int*)(ws + OFF_I);

  unsigned short* z1hi = (unsigned short*)(ws + OFF_Z1HI);
  unsigned short* z1lo = (unsigned short*)(ws + OFF_Z1LO);
  unsigned short* wt1h = (unsigned short*)(ws + OFF_WT1H);
  unsigned short* wt1l = (unsigned short*)(ws + OFF_WT1L);
  unsigned short* x2hi = (unsigned short*)(ws + OFF_X2HI);
  unsigned short* x2lo = (unsigned short*)(ws + OFF_X2LO);
  unsigned short* whi  = (unsigned short*)(ws + OFF_X);
  unsigned short* woh  = (unsigned short*)(ws + OFF_WOH);
  unsigned short* wol  = (unsigned short*)(ws + OFF_WOL);
  unsigned short* Hb   = (unsigned short*)(ws + OFF_H);
  unsigned short* x3   = (unsigned short*)(ws + OFF_X3);

  hipMemsetAsync(iws + I_DEG, 0, Nn * sizeof(int), stream);
  k_concat <<<8192, 256, 0, stream>>>(xg, ac, ti, ws + OFF_X);
  k_count  <<<128,  256, 0, stream>>>(ei, iws + I_DEG);
  k_scan   <<<1,   1024, 0, stream>>>(iws + I_DEG, iws + I_RP, iws + I_CUR);
  k_fill   <<<144,  256, 0, stream>>>(ei, iws + I_CUR, iws + I_EID);
  k_sort   <<<64,    64, 0, stream>>>(iws + I_RP, iws + I_EID);
  k_loopattr<<<256, 256, 0, stream>>>(eattr, iws + I_RP, iws + I_EID, ws + OFF_LP);

  k_proj   <<<512,  256, 0, stream>>>(W1, as1w, ad1w, ws + OFF_WS1, ws + OFF_WD1, 512, 512);
  k_proj   <<<2048, 256, 0, stream>>>(W2, as2w, ad2w, ws + OFF_WS2, ws + OFF_WD2, 2048, 2048);
  k_aeproj <<<16,   256, 0, stream>>>(We1, ae1w, ws + OFF_AE1, 512);
  k_aeproj <<<16,   256, 0, stream>>>(We2, ae2w, ws + OFF_AE2, 2048);
  k_wsplit<true, true><<<dim3(256, 8), 256, 0, stream>>>(Wout, 256, 0, 8192, woh, wol);   // fp16 [256][8192]

  // ---- layer 1 (bf16 3-term); epilogue writes x2 as fp16 hi/lo directly ----
  k_asad<false><<<4096, 256, 0, stream>>>(ws + OFF_X, nullptr, ws + OFF_WS1, ws + OFF_WD1, ws + OFF_AS1, ws + OFF_AD1, 512);
  k_edge      <<<144,  256, 0, stream>>>(eattr, ws + OFF_LP, ei, ws + OFF_AS1, ws + OFF_AD1, ws + OFF_AE1, ws + OFF_EB);
  k_softmax   <<<1024, 256, 0, stream>>>(iws + I_RP, iws + I_EID, ws + OFF_EB, ws + OFF_AL);
  k_agg1_split<<<4096, 256, 0, stream>>>(ws + OFF_X, ws + OFF_AL, iws + I_RP, iws + I_EID, ei, z1hi, z1lo);
  // X dead; wt1 overlays it
  k_wsplit<false, true><<<dim3(16, 64), 256, 0, stream>>>(W1, 2048, 0, 512, wt1h, wt1l);  // bf16 [2048][512]
  k_gemm2<512, false, false, 2, false, true, true><<<dim3(4, 32, 4), 256, 0, stream>>>(
      z1hi, z1lo, 2048, 512,  wt1h, wt1l, 512, 512*512,
      x2hi, x2lo, 2048, 512,  b1, 512);

  // ---- layer 2 attention (x2 = hi+lo fp16, reconstructed: near-exact) ----
  k_asad<true><<<4096, 256, 0, stream>>>(x2hi, x2lo, ws + OFF_WS2, ws + OFF_WD2, ws + OFF_AS2, ws + OFF_AD2, 2048);
  k_edge   <<<144,  256, 0, stream>>>(eattr, ws + OFF_LP, ei, ws + OFF_AS2, ws + OFF_AD2, ws + OFF_AE2, ws + OFF_EB);
  k_softmax<<<1024, 256, 0, stream>>>(iws + I_RP, iws + I_EID, ws + OFF_EB, ws + OFF_AL);

  // ---- layer 2 + fc, per head: H = x2@W2_h^T (fp16 MFMA), sparse agg of fp16 H, fp16 FC ----
  for (int h = 0; h < 4; ++h){
    k_wsplit<true, false><<<dim3(64, 64), 256, 0, stream>>>(W2, 8192, h*2048, 2048, whi, nullptr);
    k_gemm256 <<<dim3(8, 32), 512, 0, stream>>>(x2hi, x2lo, whi, Hb);
    k_agg2b   <<<4096, 256, 0, stream>>>(Hb, ws + OFF_AL, iws + I_RP, iws + I_EID, ei, x3, b2, h);
    if (h == 0)
      k_gemm2<512, true, true, 0, false, false, false><<<dim3(2, 32, 4), 256, 0, stream>>>(
          x3, x3, 2048, 512,  woh + (size_t)h*2048, wol + (size_t)h*2048, 8192, 512,
          ws + OFF_YP, nullptr, 256, (size_t)Nn*256,  nullptr, 0);
    else
      k_gemm2<512, true, true, 0, true, false, false><<<dim3(2, 32, 4), 256, 0, stream>>>(
          x3, x3, 2048, 512,  woh + (size_t)h*2048, wol + (size_t)h*2048, 8192, 512,
          ws + OFF_YP, nullptr, 256, (size_t)Nn*256,  nullptr, 0);
  }

  k_gsum<<<dim3(32, 8), 256, 0, stream>>>(ws + OFF_YP, bout, batch, ws + OFF_PART);
  k_gfin<<<8, 256, 0, stream>>>(ws + OFF_PART, batch, out);
}

// Round 15
// 695.642 us; speedup vs baseline: 1.0296x; 1.0292x over previous
//
#include <hip/hip_runtime.h>
#include <math.h>

constexpr int Nn  = 4096;
constexpr int Ne  = 32768;
constexpr int NEf = Ne + Nn;     // real edges + self loops

// ---------------- ws layout (float offsets) ----------------
constexpr size_t OFF_X    = 0;
constexpr size_t OFF_WT1H = 0;
constexpr size_t OFF_WT1L = 524288;
constexpr size_t OFF_Z1HI = 2097152;
constexpr size_t OFF_Z1LO = 6291456;
constexpr size_t OFF_X3   = 2097152;     // ushort region (fp16), overlays dead z1
constexpr size_t OFF_PART = 2097152;     // fp32, overlays dead x3 (final)
constexpr size_t OFF_X2HI = 10485760;    // ushort region
constexpr size_t OFF_X2LO = 14680064;    // ushort region
constexpr size_t OFF_H    = 18874368;    // ushort region (fp16) [4096][2048]
constexpr size_t OFF_WOH  = 25165824;    // ushort region [256][8192] fp16
constexpr size_t OFF_WOL  = 26214400;    // ushort region
constexpr size_t OFF_YP   = 27262976;
constexpr size_t OFF_LP  = 31457280;     // [N,16] self-loop edge attr
constexpr size_t OFF_WS1 = OFF_LP  + 65536;   // [512,4]
constexpr size_t OFF_WD1 = OFF_WS1 + 2048;    // [512,4]
constexpr size_t OFF_WS2 = OFF_WD1 + 2048;    // [2048,4]
constexpr size_t OFF_WD2 = OFF_WS2 + 8192;    // [2048,4]
constexpr size_t OFF_AE1 = OFF_WD2 + 8192;    // [16,4]
constexpr size_t OFF_AE2 = OFF_AE1 + 64;      // [16,4]
constexpr size_t OFF_AS1 = OFF_AE2 + 64;      // [N,4]
constexpr size_t OFF_AD1 = OFF_AS1 + 16384;
constexpr size_t OFF_AS2 = OFF_AD1 + 16384;
constexpr size_t OFF_AD2 = OFF_AS2 + 16384;
constexpr size_t OFF_EB  = OFF_AD2 + 16384;          // [Ef,4] logits
constexpr size_t OFF_AL  = OFF_EB  + (size_t)NEf*4;  // [Ef,4] alpha
constexpr size_t OFF_I   = OFF_AL  + (size_t)NEf*4;  // int region
constexpr size_t I_DEG = 0;       // [N]
constexpr size_t I_RP  = 4096;    // [N+1] (+pad)
constexpr size_t I_CUR = 8200;    // [N]
constexpr size_t I_EID = 12296;   // [Ef]
constexpr size_t WS_FLOATS = OFF_I + I_EID + (size_t)NEf + 64;

using bf16x8 = __bf16 __attribute__((ext_vector_type(8)));
using f16x8  = _Float16 __attribute__((ext_vector_type(8)));
using f32x4  = float __attribute__((ext_vector_type(4)));

__device__ __forceinline__ float wred64(float v){
#pragma unroll
  for (int o = 32; o > 0; o >>= 1) v += __shfl_down(v, o, 64);
  return v;
}
__device__ __forceinline__ float lrelu(float v, float s){ return v > 0.f ? v : s * v; }

__device__ __forceinline__ unsigned short f2bf(float x){  // RTNE
  unsigned int u = __float_as_uint(x);
  unsigned int r = (u + 0x7FFFu + ((u >> 16) & 1u)) >> 16;
  return (unsigned short)r;
}
__device__ __forceinline__ float bf2f(unsigned short h){
  return __uint_as_float((unsigned int)h << 16);
}
__device__ __forceinline__ void split2(float x, unsigned short& h, unsigned short& l){
  h = f2bf(x);
  l = f2bf(x - bf2f(h));
}
__device__ __forceinline__ unsigned short f2h(float x){
  _Float16 h = (_Float16)x;
  return __builtin_bit_cast(unsigned short, h);
}
__device__ __forceinline__ float h2f(unsigned short u){
  return (float)__builtin_bit_cast(_Float16, u);
}
__device__ __forceinline__ void split2h(float x, unsigned short& h, unsigned short& l){
  _Float16 hh = (_Float16)x;
  h = __builtin_bit_cast(unsigned short, hh);
  _Float16 ll = (_Float16)(x - (float)hh);
  l = __builtin_bit_cast(unsigned short, ll);
}
__device__ __forceinline__ void gload16(const void* g, void* l){
  __builtin_amdgcn_global_load_lds((const __attribute__((address_space(1))) void*)g,
                                   (__attribute__((address_space(3))) void*)l, 16, 0, 0);
}

// ---------------- small prep kernels ----------------
__global__ void k_concat(const float* __restrict__ xg, const float* __restrict__ ac,
                         const float* __restrict__ ti, float* __restrict__ x){
  int i = blockIdx.x * 256 + threadIdx.x;          // over N*512
  int n = i >> 9, c = i & 511;
  float v;
  if (c < 256)      v = xg[(size_t)n*256 + c];
  else if (c < 384) v = ac[(size_t)n*128 + (c-256)];
  else              v = ti[(size_t)n*128 + (c-384)];
  x[i] = v;
}

__global__ void k_count(const int* __restrict__ ei, int* __restrict__ deg){
  int e = blockIdx.x * 256 + threadIdx.x;
  if (e < Ne) atomicAdd(&deg[ei[Ne + e]], 1);
}

__global__ void k_scan(const int* __restrict__ deg, int* __restrict__ rowptr, int* __restrict__ cursor){
  __shared__ int sd[1024];
  int t = threadIdx.x;
  int v[4]; int s = 0;
#pragma unroll
  for (int i = 0; i < 4; i++){ v[i] = s; s += deg[t*4 + i] + 1; }   // +1 self loop
  sd[t] = s;
  __syncthreads();
  for (int off = 1; off < 1024; off <<= 1){
    int x = (t >= off) ? sd[t - off] : 0;
    __syncthreads();
    sd[t] += x;
    __syncthreads();
  }
  int base = (t == 0) ? 0 : sd[t - 1];
#pragma unroll
  for (int i = 0; i < 4; i++){ int rp = base + v[i]; rowptr[t*4 + i] = rp; cursor[t*4 + i] = rp; }
  if (t == 1023) rowptr[4096] = sd[1023];
}

__global__ void k_fill(const int* __restrict__ ei, int* __restrict__ cursor, int* __restrict__ eids){
  int e = blockIdx.x * 256 + threadIdx.x;
  if (e >= NEf) return;
  int d = (e < Ne) ? ei[Ne + e] : (e - Ne);
  int p = atomicAdd(&cursor[d], 1);
  eids[p] = e;
}

__global__ void k_sort(const int* __restrict__ rowptr, int* __restrict__ eids){
  int n = blockIdx.x * 64 + threadIdx.x;
  if (n >= Nn) return;
  int b = rowptr[n], e = rowptr[n + 1];
  for (int i = b + 1; i < e; i++){
    int key = eids[i]; int j = i - 1;
    while (j >= b && eids[j] > key){ eids[j+1] = eids[j]; j--; }
    eids[j+1] = key;
  }
}

__global__ void k_loopattr(const float* __restrict__ eattr, const int* __restrict__ rowptr,
                           const int* __restrict__ eids, float* __restrict__ lp){
  int idx = blockIdx.x * 256 + threadIdx.x;        // N*16
  int n = idx >> 4, a = idx & 15;
  if (n >= Nn) return;
  int b = rowptr[n], e = rowptr[n + 1];
  float s = 0.f; int cnt = 0;
  for (int j = b; j < e; ++j){
    int id = eids[j];
    if (id < Ne){ s += eattr[(size_t)id*16 + a]; cnt++; }
  }
  lp[(size_t)n*16 + a] = s / fmaxf((float)cnt, 1.f);
}

// Ws[k,h] = sum_c W[k, h*C+c]*a_s[h,c] ; Wd likewise.
__global__ void k_proj(const float* __restrict__ W, const float* __restrict__ a_s,
                       const float* __restrict__ a_d, float* __restrict__ Ws,
                       float* __restrict__ Wd, int K, int C){
  int gid = blockIdx.x * 256 + threadIdx.x;
  int wave = gid >> 6, lane = gid & 63;
  int h = wave & 3, k = wave >> 2;
  if (k >= K) return;
  const float* wrow = W + (size_t)k * (4*C) + (size_t)h * C;
  const float* ar = a_s + (size_t)h * C;
  const float* dr = a_d + (size_t)h * C;
  float ps = 0.f, pd = 0.f;
  for (int c = lane; c < C; c += 64){ float w = wrow[c]; ps += w * ar[c]; pd += w * dr[c]; }
  ps = wred64(ps); pd = wred64(pd);
  if (lane == 0){ Ws[k*4 + h] = ps; Wd[k*4 + h] = pd; }
}

// one wave per (k,h): outp[k*4+h] = dot(We[k, h*C:(h+1)*C], ae[h,:])
__global__ void k_aeproj(const float* __restrict__ We, const float* __restrict__ ae,
                         float* __restrict__ outp, int C){
  int gid = blockIdx.x * 256 + threadIdx.x;
  int wave = gid >> 6, lane = gid & 63;
  int h = wave & 3, k = wave >> 2;
  if (k >= 16) return;
  const float* wrow = We + (size_t)k * (4*C) + (size_t)h * C;
  const float* ar = ae + (size_t)h * C;
  float s = 0.f;
  for (int c = lane; c < C; c += 64) s += wrow[c] * ar[c];
  s = wred64(s);
  if (lane == 0) outp[k*4 + h] = s;
}

// as[n,h], ad[n,h] = x[n,:] @ Ws/Wd. Block per node.
template<bool HALF>
__global__ __launch_bounds__(256) void k_asad(const void* __restrict__ xp, const void* __restrict__ xlp,
                      const float* __restrict__ Ws,
                      const float* __restrict__ Wd, float* __restrict__ as_,
                      float* __restrict__ ad_, int D){
  int n = blockIdx.x, t = threadIdx.x;
  float p[8] = {0,0,0,0,0,0,0,0};
  if (HALF){
    const unsigned short* rh = (const unsigned short*)xp + (size_t)n * D;
    const unsigned short* rl = (const unsigned short*)xlp + (size_t)n * D;
    for (int c = t; c < D; c += 256){
      float xv = h2f(rh[c]) + h2f(rl[c]);
      float4 ws4 = *(const float4*)&Ws[c*4];
      float4 wd4 = *(const float4*)&Wd[c*4];
      p[0] += xv * ws4.x; p[1] += xv * ws4.y; p[2] += xv * ws4.z; p[3] += xv * ws4.w;
      p[4] += xv * wd4.x; p[5] += xv * wd4.y; p[6] += xv * wd4.z; p[7] += xv * wd4.w;
    }
  } else {
    const float* row = (const float*)xp + (size_t)n * D;
    for (int c = t; c < D; c += 256){
      float xv = row[c];
      float4 ws4 = *(const float4*)&Ws[c*4];
      float4 wd4 = *(const float4*)&Wd[c*4];
      p[0] += xv * ws4.x; p[1] += xv * ws4.y; p[2] += xv * ws4.z; p[3] += xv * ws4.w;
      p[4] += xv * wd4.x; p[5] += xv * wd4.y; p[6] += xv * wd4.z; p[7] += xv * wd4.w;
    }
  }
  __shared__ float sm[4][8];
  int lane = t & 63, wid = t >> 6;
#pragma unroll
  for (int q = 0; q < 8; q++){
    float v = wred64(p[q]);
    if (lane == 0) sm[wid][q] = v;
  }
  __syncthreads();
  if (t < 8){
    float s = sm[0][t] + sm[1][t] + sm[2][t] + sm[3][t];
    if (t < 4) as_[(size_t)n*4 + t] = s;
    else       ad_[(size_t)n*4 + (t-4)] = s;
  }
}

__global__ void k_edge(const float* __restrict__ eattr, const float* __restrict__ lp,
                       const int* __restrict__ ei, const float* __restrict__ as_,
                       const float* __restrict__ ad_, const float* __restrict__ aep,
                       float* __restrict__ ebuf){
  int e = blockIdx.x * 256 + threadIdx.x;
  if (e >= NEf) return;
  int s, d; const float* ea;
  if (e < Ne){ s = ei[e]; d = ei[Ne + e]; ea = eattr + (size_t)e * 16; }
  else { s = e - Ne; d = e - Ne; ea = lp + (size_t)(e - Ne) * 16; }
  float eav[16];
#pragma unroll
  for (int k = 0; k < 16; k++) eav[k] = ea[k];
#pragma unroll
  for (int h = 0; h < 4; h++){
    float v = as_[(size_t)s*4 + h] + ad_[(size_t)d*4 + h];
#pragma unroll
    for (int k = 0; k < 16; k++) v += eav[k] * aep[k*4 + h];
    ebuf[(size_t)e*4 + h] = lrelu(v, 0.2f);
  }
}

// wave-per-node softmax: 4 waves/block, 1024 blocks.
__global__ __launch_bounds__(256) void k_softmax(const int* __restrict__ rowptr, const int* __restrict__ eids,
                          const float* __restrict__ ebuf, float* __restrict__ alpha){
  const int wid = threadIdx.x >> 6, lane = threadIdx.x & 63;
  const int n = blockIdx.x * 4 + wid;
  const int b = rowptr[n], e = rowptr[n + 1];
  float4 m = {-1e30f, -1e30f, -1e30f, -1e30f};
  for (int j = b + lane; j < e; j += 64){
    float4 ev = *(const float4*)&ebuf[(size_t)eids[j]*4];
    m.x = fmaxf(m.x, ev.x); m.y = fmaxf(m.y, ev.y);
    m.z = fmaxf(m.z, ev.z); m.w = fmaxf(m.w, ev.w);
  }
#pragma unroll
  for (int o = 32; o > 0; o >>= 1){
    m.x = fmaxf(m.x, __shfl_xor(m.x, o, 64));
    m.y = fmaxf(m.y, __shfl_xor(m.y, o, 64));
    m.z = fmaxf(m.z, __shfl_xor(m.z, o, 64));
    m.w = fmaxf(m.w, __shfl_xor(m.w, o, 64));
  }
  float4 s = {0.f, 0.f, 0.f, 0.f};
  for (int j = b + lane; j < e; j += 64){
    int eid = eids[j];
    float4 ev = *(const float4*)&ebuf[(size_t)eid*4];
    float4 ex = { expf(ev.x - m.x), expf(ev.y - m.y), expf(ev.z - m.z), expf(ev.w - m.w) };
    *(float4*)&alpha[(size_t)eid*4] = ex;
    s.x += ex.x; s.y += ex.y; s.z += ex.z; s.w += ex.w;
  }
#pragma unroll
  for (int o = 32; o > 0; o >>= 1){
    s.x += __shfl_xor(s.x, o, 64);
    s.y += __shfl_xor(s.y, o, 64);
    s.z += __shfl_xor(s.z, o, 64);
    s.w += __shfl_xor(s.w, o, 64);
  }
  float4 r = { 1.f/s.x, 1.f/s.y, 1.f/s.z, 1.f/s.w };
  for (int j = b + lane; j < e; j += 64){
    int eid = eids[j];
    float4 av = *(const float4*)&alpha[(size_t)eid*4];
    av.x *= r.x; av.y *= r.y; av.z *= r.z; av.w *= r.w;
    *(float4*)&alpha[(size_t)eid*4] = av;
  }
}

// z1[n, h*512+c] = sum_e alpha[e,h] * x[src(e),c], bf16 hi/lo split out.
// Edge ids/alpha preloaded to LDS (removes 256x-redundant uniform loads).
__global__ __launch_bounds__(256) void k_agg1_split(const float* __restrict__ x, const float* __restrict__ alpha,
                      const int* __restrict__ rowptr, const int* __restrict__ eids,
                      const int* __restrict__ ei, unsigned short* __restrict__ z1hi,
                      unsigned short* __restrict__ z1lo){
  __shared__ float4 sal[128];
  __shared__ int    ssrc[128];
  int n = blockIdx.x, t = threadIdx.x;
  float2 a0 = {0,0}, a1 = {0,0}, a2 = {0,0}, a3 = {0,0};
  int b = rowptr[n], e = rowptr[n + 1];
  for (int c0 = b; c0 < e; c0 += 128){
    int cnt = min(e - c0, 128);
    __syncthreads();
    if (t < cnt){
      int eid = eids[c0 + t];
      ssrc[t] = (eid < Ne) ? ei[eid] : (eid - Ne);
      sal[t]  = *(const float4*)&alpha[(size_t)eid*4];
    }
    __syncthreads();
    for (int j = 0; j < cnt; ++j){
      float4 av = sal[j];
      float2 xv = *(const float2*)&x[(size_t)ssrc[j]*512 + t*2];
      a0.x += av.x*xv.x; a0.y += av.x*xv.y;
      a1.x += av.y*xv.x; a1.y += av.y*xv.y;
      a2.x += av.z*xv.x; a2.y += av.z*xv.y;
      a3.x += av.w*xv.x; a3.y += av.w*xv.y;
    }
  }
  size_t base = (size_t)n*2048 + t*2;
  float2 av[4] = {a0, a1, a2, a3};
#pragma unroll
  for (int h = 0; h < 4; h++){
    ushort2 hh, ll;
    split2(av[h].x, hh.x, ll.x);
    split2(av[h].y, hh.y, ll.y);
    *(ushort2*)&z1hi[base + h*512] = hh;
    *(ushort2*)&z1lo[base + h*512] = ll;
  }
}

// x3[n,:] = lrelu( sum_e alpha[e,h]*H[src,:] + b2_h, 0.01 ), fp16 in/out. Block per dst node.
// Edge ids/alpha preloaded to LDS.
__global__ __launch_bounds__(256) void k_agg2b(const unsigned short* __restrict__ H,
                      const float* __restrict__ alpha,
                      const int* __restrict__ rowptr, const int* __restrict__ eids,
                      const int* __restrict__ ei, unsigned short* __restrict__ x3,
                      const float* __restrict__ b2, int h){
  __shared__ float sal[128];
  __shared__ int   ssrc[128];
  int n = blockIdx.x, t = threadIdx.x;
  float acc[8] = {0,0,0,0,0,0,0,0};
  int b = rowptr[n], e = rowptr[n + 1];
  for (int c0 = b; c0 < e; c0 += 128){
    int cnt = min(e - c0, 128);
    __syncthreads();
    if (t < cnt){
      int eid = eids[c0 + t];
      ssrc[t] = (eid < Ne) ? ei[eid] : (eid - Ne);
      sal[t]  = alpha[(size_t)eid*4 + h];
    }
    __syncthreads();
    for (int j = 0; j < cnt; ++j){
      float a = sal[j];
      f16x8 hv = *(const f16x8*)&H[(size_t)ssrc[j]*2048 + t*8];
#pragma unroll
      for (int q = 0; q < 8; q++) acc[q] += a * (float)hv[q];
    }
  }
  const float* bb = b2 + (size_t)h*2048 + t*8;
  ushort4 o0, o1;
  float4 b0 = *(const float4*)bb;
  float4 b1 = *(const float4*)(bb + 4);
  o0.x = f2h(lrelu(acc[0] + b0.x, 0.01f)); o0.y = f2h(lrelu(acc[1] + b0.y, 0.01f));
  o0.z = f2h(lrelu(acc[2] + b0.z, 0.01f)); o0.w = f2h(lrelu(acc[3] + b0.w, 0.01f));
  o1.x = f2h(lrelu(acc[4] + b1.x, 0.01f)); o1.y = f2h(lrelu(acc[5] + b1.y, 0.01f));
  o1.z = f2h(lrelu(acc[6] + b1.z, 0.01f)); o1.w = f2h(lrelu(acc[7] + b1.w, 0.01f));
  size_t base = (size_t)n*2048 + t*8;
  *(ushort4*)&x3[base]     = o0;
  *(ushort4*)&x3[base + 4] = o1;
}

// transpose + split: out[col][k] = split(W[k][coloff+col]); out stride K.
template<bool HALF, bool STORELO>
__global__ __launch_bounds__(256) void k_wsplit(const float* __restrict__ W, int ldw, int coloff, int K,
                       unsigned short* __restrict__ whi, unsigned short* __restrict__ wlo){
  __shared__ float tile[32][33];
  int bk = blockIdx.x * 32, bn = blockIdx.y * 32;
  int tx = threadIdx.x & 31, ty = threadIdx.x >> 5;
#pragma unroll
  for (int i = 0; i < 4; i++){
    int k = bk + ty + i*8;
    tile[ty + i*8][tx] = W[(size_t)k*ldw + coloff + bn + tx];
  }
  __syncthreads();
#pragma unroll
  for (int i = 0; i < 4; i++){
    int n = bn + ty + i*8;
    float v = tile[tx][ty + i*8];
    unsigned short hh, ll;
    if (HALF) split2h(v, hh, ll); else split2(v, hh, ll);
    whi[(size_t)n*K + bk + tx] = hh;
    if (STORELO) wlo[(size_t)n*K + bk + tx] = ll;
  }
}

// ---------------- L2 dense GEMM: r15 register-pipelined ----------------
// H[4096][2048] = x2[4096][2048k] x W2h^T[2048n][2048k]; fp16 2-term C = Ah*Bh + Al*Bh.
// BM=128, BN=256, 8 waves, 3 LDS buffers (96KB). Software pipeline (per step kt):
//   gload tile kt+3 -> buf[kt%3] (freed: its frags consumed at kt-1)
//   ds_read frags(kt+1) from buf[(kt+1)%3] (landed at end of kt-1)
//   MFMA(kt) from REGISTERS (loaded last step)  -> LDS latency hides under MFMA
//   lgkmcnt(0) (frags landed before their buffer is overwritten next step)
//   vmcnt(4) (drains tile kt+2 for next step's ds_read); barrier; sched_barrier.
// Register double-buffer: named A/B sets, unroll-2 (no runtime-indexed frag arrays).
__global__ __launch_bounds__(512) void k_gemm256(
    const unsigned short* __restrict__ Ah, const unsigned short* __restrict__ Al,
    const unsigned short* __restrict__ Bh, unsigned short* __restrict__ Cout)
{
  __shared__ __align__(16) unsigned short lds[49152];   // 3 x (A 8192 + B 8192) ushorts
  const int t = threadIdx.x;
  const int bid = blockIdx.y * 8 + blockIdx.x;
  const int sbid = (bid & 7) * 32 + (bid >> 3);         // XCD-chunked swizzle
  const int brow = (sbid >> 3) * 128, bcol = (sbid & 7) * 256;
  const int w = t >> 6, lane = t & 63;
  const int wm = (w >> 2) * 64, wn = (w & 3) * 64;
  constexpr int BUF = 16384, BOFF = 8192;   // ushorts

  // A staging: row = i*64+(t>>3), phys chunk t&7, logical = phys^(row&7)
  const int asr = t >> 3;
  const int ascc = (t & 7) ^ (asr & 7);
  const unsigned short* asrc = (ascc < 4 ? Ah : Al) + (size_t)(brow + asr)*2048 + (size_t)(ascc & 3)*8;
  // B staging: row = i*128+(t>>2), phys chunk t&3, logical = phys^((row>>1)&3)
  const int bsr = t >> 2;
  const int bscc = (t & 3) ^ ((bsr >> 1) & 3);
  const unsigned short* bsrc = Bh + (size_t)(bcol + bsr)*2048 + (size_t)bscc*8;
  const int adst = w * 512;           // + buf*BUF + i*4096 (+ lane*16B implicit)
  const int bdst = BOFF + w * 512;

  const int fr = lane & 15, kc = lane >> 4;
  const int aswz = (kc ^ (lane & 7)) * 8;
  const int bswz = (kc ^ ((lane >> 1) & 3)) * 8;
  int aoff[4], boff[4];
#pragma unroll
  for (int m = 0; m < 4; m++) aoff[m] = (wm + m*16 + fr)*64 + aswz;
#pragma unroll
  for (int n = 0; n < 4; n++) boff[n] = BOFF + (wn + n*16 + fr)*32 + bswz;

  f32x4 acc[4][4];
#pragma unroll
  for (int m = 0; m < 4; m++)
#pragma unroll
    for (int n = 0; n < 4; n++) acc[m][n] = f32x4{0.f, 0.f, 0.f, 0.f};

  f16x8 ahA[4], alA[4], bfA[4], ahB[4], alB[4], bfB[4];

  // prologue: stage tiles 0,1,2 tile-by-tile; vmcnt(4) => tiles 0,1 landed.
#pragma unroll
  for (int tl = 0; tl < 3; ++tl){
    const int bb = tl * BUF;
    const size_t ko = (size_t)tl * 32;
    gload16(asrc + ko,                    &lds[bb + adst]);
    gload16(asrc + (size_t)64*2048 + ko,  &lds[bb + 4096 + adst]);
    gload16(bsrc + ko,                    &lds[bb + bdst]);
    gload16(bsrc + (size_t)128*2048 + ko, &lds[bb + 4096 + bdst]);
  }
  asm volatile("s_waitcnt vmcnt(4)" ::: "memory");
  __builtin_amdgcn_s_barrier();
  __builtin_amdgcn_sched_barrier(0);
  // frags(0) into set A
#pragma unroll
  for (int m = 0; m < 4; m++){
    ahA[m] = *(const f16x8*)&lds[aoff[m]];
    alA[m] = *(const f16x8*)&lds[aoff[m] ^ 32];
  }
#pragma unroll
  for (int n = 0; n < 4; n++) bfA[n] = *(const f16x8*)&lds[boff[n]];
  asm volatile("s_waitcnt lgkmcnt(0)" ::: "memory");
  __builtin_amdgcn_sched_barrier(0);

  auto step = [&](int kt_, f16x8 (&ahC)[4], f16x8 (&alC)[4], f16x8 (&bfC)[4],
                          f16x8 (&ahN)[4], f16x8 (&alN)[4], f16x8 (&bfN)[4]){
    if (kt_ + 3 < 64){
      const int nbo = ((kt_ + 3) % 3) * BUF;
      const size_t nko = (size_t)(kt_ + 3) * 32;
      gload16(asrc + nko,                    &lds[nbo + adst]);
      gload16(asrc + (size_t)64*2048 + nko,  &lds[nbo + 4096 + adst]);
      gload16(bsrc + nko,                    &lds[nbo + bdst]);
      gload16(bsrc + (size_t)128*2048 + nko, &lds[nbo + 4096 + bdst]);
    }
    if (kt_ + 1 < 64){
      const int nxb = ((kt_ + 1) % 3) * BUF;
#pragma unroll
      for (int m = 0; m < 4; m++){
        ahN[m] = *(const f16x8*)&lds[nxb + aoff[m]];
        alN[m] = *(const f16x8*)&lds[nxb + (aoff[m] ^ 32)];
      }
#pragma unroll
      for (int n = 0; n < 4; n++) bfN[n] = *(const f16x8*)&lds[nxb + boff[n]];
    }
    __builtin_amdgcn_s_setprio(1);
#pragma unroll
    for (int n = 0; n < 4; n++){
#pragma unroll
      for (int m = 0; m < 4; m++) acc[m][n] = __builtin_amdgcn_mfma_f32_16x16x32_f16(ahC[m], bfC[n], acc[m][n], 0, 0, 0);
#pragma unroll
      for (int m = 0; m < 4; m++) acc[m][n] = __builtin_amdgcn_mfma_f32_16x16x32_f16(alC[m], bfC[n], acc[m][n], 0, 0, 0);
    }
    __builtin_amdgcn_s_setprio(0);
    asm volatile("s_waitcnt lgkmcnt(0)" ::: "memory");
    if (kt_ + 3 < 64) asm volatile("s_waitcnt vmcnt(4)" ::: "memory");
    else              asm volatile("s_waitcnt vmcnt(0)" ::: "memory");
    __builtin_amdgcn_s_barrier();
    __builtin_amdgcn_sched_barrier(0);
  };

  for (int kt = 0; kt < 64; kt += 2){
    step(kt,     ahA, alA, bfA, ahB, alB, bfB);
    step(kt + 1, ahB, alB, bfB, ahA, alA, bfA);
  }

  // ---- epilogue: fp16 store. C/D frag: col=lane&15, row=(lane>>4)*4+reg
#pragma unroll
  for (int m = 0; m < 4; m++){
    const int row0 = brow + wm + m*16 + kc*4;
#pragma unroll
    for (int n = 0; n < 4; n++){
      const int col = bcol + wn + n*16 + fr;
#pragma unroll
      for (int r = 0; r < 4; r++)
        Cout[(size_t)(row0 + r)*2048 + col] = f2h(acc[m][n][r]);
    }
  }
}

// ---------------- MFMA GEMM (128x128): bf16 3-term, or fp16 exact-A 2-term ----------------
// OUTMODE: 0 = fp32 (+BETA1), 1 = bf16, 2 = fp16 hi/lo split to Cout/Cout2
template<int KLEN, bool EXACTA, bool HALF, int OUTMODE, bool BETA1, bool ACT, bool HASBIAS>
__global__ __launch_bounds__(256) void k_gemm2(
    const unsigned short* __restrict__ Ah, const unsigned short* __restrict__ Al, int lda, size_t az,
    const unsigned short* __restrict__ Bh, const unsigned short* __restrict__ Bl, int ldb, size_t bz,
    void* __restrict__ Cout, void* __restrict__ Cout2, int ldc, size_t cz,
    const float* __restrict__ bias, size_t biasz)
{
  __shared__ unsigned short lds[16384];   // A: [0,8192) ushorts, B: [8192,16384)
  const int t = threadIdx.x;
  const int z = blockIdx.z;
  const int brow = blockIdx.y * 128, bcol = blockIdx.x * 128;
  const int wid = t >> 6, lane = t & 63;
  const int wm = (wid >> 1) * 64, wn = (wid & 1) * 64;

  const int sr = t >> 3, sc = t & 7;
  const int scc = sc ^ (sr & 7);
  const unsigned short* asrc = (scc < 4 ? Ah : Al) + (size_t)(brow + sr)*lda + (size_t)z*az + (size_t)(scc & 3)*8;
  const unsigned short* bsrc = (scc < 4 ? Bh : Bl) + (size_t)(bcol + sr)*ldb + (size_t)z*bz + (size_t)(scc & 3)*8;
  unsigned short* adst = &lds[(size_t)wid * 512];
  unsigned short* bdst = &lds[8192 + (size_t)wid * 512];

  const int fr = lane & 15, kc = lane >> 4;
  const int swz = ((kc ^ (lane & 7)) << 3);
  int aoff[4], boff[4];
#pragma unroll
  for (int m = 0; m < 4; m++) aoff[m] = (wm + m*16 + fr)*64 + swz;
#pragma unroll
  for (int n = 0; n < 4; n++) boff[n] = 8192 + (wn + n*16 + fr)*64 + swz;

  f32x4 acc[4][4];
#pragma unroll
  for (int m = 0; m < 4; m++)
#pragma unroll
    for (int n = 0; n < 4; n++) acc[m][n] = f32x4{0.f, 0.f, 0.f, 0.f};

  for (int kt = 0; kt < KLEN/32; ++kt){
    const size_t ko = (size_t)kt * 32;
#pragma unroll
    for (int i = 0; i < 4; i++){
      gload16(asrc + (size_t)i*32*lda + ko, adst + i*2048);
      gload16(bsrc + (size_t)i*32*ldb + ko, bdst + i*2048);
    }
    __syncthreads();

    if (HALF){
      f16x8 ah[4], bh[4], bl[4];
#pragma unroll
      for (int m = 0; m < 4; m++) ah[m] = *(const f16x8*)&lds[aoff[m]];
#pragma unroll
      for (int n = 0; n < 4; n++){
        bh[n] = *(const f16x8*)&lds[boff[n]];
        bl[n] = *(const f16x8*)&lds[boff[n] ^ 32];
      }
#pragma unroll
      for (int m = 0; m < 4; m++)
#pragma unroll
        for (int n = 0; n < 4; n++){
          acc[m][n] = __builtin_amdgcn_mfma_f32_16x16x32_f16(ah[m], bh[n], acc[m][n], 0, 0, 0);
          acc[m][n] = __builtin_amdgcn_mfma_f32_16x16x32_f16(ah[m], bl[n], acc[m][n], 0, 0, 0);
        }
    } else {
      bf16x8 ah[4], al[4], bh[4], bl[4];
#pragma unroll
      for (int m = 0; m < 4; m++){
        ah[m] = *(const bf16x8*)&lds[aoff[m]];
        if (!EXACTA) al[m] = *(const bf16x8*)&lds[aoff[m] ^ 32];
      }
#pragma unroll
      for (int n = 0; n < 4; n++){
        bh[n] = *(const bf16x8*)&lds[boff[n]];
        bl[n] = *(const bf16x8*)&lds[boff[n] ^ 32];
      }
#pragma unroll
      for (int m = 0; m < 4; m++)
#pragma unroll
        for (int n = 0; n < 4; n++){
          acc[m][n] = __builtin_amdgcn_mfma_f32_16x16x32_bf16(ah[m], bh[n], acc[m][n], 0, 0, 0);
          acc[m][n] = __builtin_amdgcn_mfma_f32_16x16x32_bf16(ah[m], bl[n], acc[m][n], 0, 0, 0);
          if (!EXACTA)
            acc[m][n] = __builtin_amdgcn_mfma_f32_16x16x32_bf16(al[m], bh[n], acc[m][n], 0, 0, 0);
        }
    }
    __syncthreads();
  }

  float bv[4] = {0.f, 0.f, 0.f, 0.f};
  if (HASBIAS){
#pragma unroll
    for (int n = 0; n < 4; n++) bv[n] = bias[(size_t)z*biasz + bcol + wn + n*16 + fr];
  }
  float* Cf = (float*)Cout + (size_t)z*cz;
  unsigned short* Cb = (unsigned short*)Cout + (size_t)z*cz;
  unsigned short* Cl = (unsigned short*)Cout2 + (size_t)z*cz;
#pragma unroll
  for (int m = 0; m < 4; m++){
    const int row0 = brow + wm + m*16 + kc*4;
#pragma unroll
    for (int n = 0; n < 4; n++){
      const int col = bcol + wn + n*16 + fr;
#pragma unroll
      for (int r = 0; r < 4; r++){
        float v = acc[m][n][r] + bv[n];
        if (ACT) v = lrelu(v, 0.01f);
        size_t idx = (size_t)(row0 + r)*ldc + col;
        if (OUTMODE == 0){
          float* cp = &Cf[idx];
          if (BETA1) v += *cp;
          *cp = v;
        } else if (OUTMODE == 1){
          Cb[idx] = f2bf(v);
        } else {
          unsigned short hh, ll; split2h(v, hh, ll);
          Cb[idx] = hh; Cl[idx] = ll;
        }
      }
    }
  }
}

// stage 1: per (slice, graph) partial sums over stride-32 node slices
__global__ void k_gsum(const float* __restrict__ yp, const float* __restrict__ bout,
                       const int* __restrict__ batch, float* __restrict__ part){
  const int s = blockIdx.x, g = blockIdx.y, t = threadIdx.x;
  __shared__ int sb[2];
  if (t < 2){
    int key = g + t, lo = 0, hi = Nn;
    while (lo < hi){ int mid = (lo + hi) >> 1; if (batch[mid] < key) lo = mid + 1; else hi = mid; }
    sb[t] = lo;
  }
  __syncthreads();
  const int b = sb[0], e = sb[1];
  const size_t P = (size_t)Nn * 256;
  float acc = 0.f;
  float bt = bout[t];
  for (int n = b + s; n < e; n += 32){
    size_t i = (size_t)n*256 + t;
    float v = yp[i] + yp[P + i] + yp[2*P + i] + yp[3*P + i] + bt;
    acc += lrelu(v, 0.01f);
  }
  part[(size_t)(g*32 + s)*256 + t] = acc;
}

// stage 2: sum 32 slices, divide by count
__global__ void k_gfin(const float* __restrict__ part, const int* __restrict__ batch,
                       float* __restrict__ out){
  const int g = blockIdx.x, t = threadIdx.x;
  __shared__ int sb[2];
  if (t < 2){
    int key = g + t, lo = 0, hi = Nn;
    while (lo < hi){ int mid = (lo + hi) >> 1; if (batch[mid] < key) lo = mid + 1; else hi = mid; }
    sb[t] = lo;
  }
  __syncthreads();
  const int cnt = sb[1] - sb[0];
  float s = 0.f;
#pragma unroll
  for (int k = 0; k < 32; k++) s += part[(size_t)(g*32 + k)*256 + t];
  out[g*256 + t] = s / fmaxf((float)cnt, 1.f);
}

// ---------------- launch ----------------
extern "C" void kernel_launch(void* const* d_in, const int* in_sizes, int n_in,
                              void* d_out, int out_size, void* d_ws, size_t ws_size,
                              hipStream_t stream){
  const float* xg    = (const float*)d_in[0];
  const float* ac    = (const float*)d_in[1];
  const float* ti    = (const float*)d_in[2];
  const float* eattr = (const float*)d_in[3];
  const int*   ei    = (const int*)  d_in[4];
  const int*   batch = (const int*)  d_in[5];
  const float* W1    = (const float*)d_in[6];
  const float* as1w  = (const float*)d_in[7];
  const float* ad1w  = (const float*)d_in[8];
  const float* ae1w  = (const float*)d_in[9];
  const float* We1   = (const float*)d_in[10];
  const float* b1    = (const float*)d_in[11];
  const float* W2    = (const float*)d_in[12];
  const float* as2w  = (const float*)d_in[13];
  const float* ad2w  = (const float*)d_in[14];
  const float* ae2w  = (const float*)d_in[15];
  const float* We2   = (const float*)d_in[16];
  const float* b2    = (const float*)d_in[17];
  const float* Wout  = (const float*)d_in[18];
  const float* bout  = (const float*)d_in[19];
  float* out = (float*)d_out;
  float* ws  = (float*)d_ws;
  if (ws_size < WS_FLOATS * sizeof(float)) return;
  int* iws = (int*)(ws + OFF_I);

  unsigned short* z1hi = (unsigned short*)(ws + OFF_Z1HI);
  unsigned short* z1lo = (unsigned short*)(ws + OFF_Z1LO);
  unsigned short* wt1h = (unsigned short*)(ws + OFF_WT1H);
  unsigned short* wt1l = (unsigned short*)(ws + OFF_WT1L);
  unsigned short* x2hi = (unsigned short*)(ws + OFF_X2HI);
  unsigned short* x2lo = (unsigned short*)(ws + OFF_X2LO);
  unsigned short* whi  = (unsigned short*)(ws + OFF_X);
  unsigned short* woh  = (unsigned short*)(ws + OFF_WOH);
  unsigned short* wol  = (unsigned short*)(ws + OFF_WOL);
  unsigned short* Hb   = (unsigned short*)(ws + OFF_H);
  unsigned short* x3   = (unsigned short*)(ws + OFF_X3);

  hipMemsetAsync(iws + I_DEG, 0, Nn * sizeof(int), stream);
  k_concat <<<8192, 256, 0, stream>>>(xg, ac, ti, ws + OFF_X);
  k_count  <<<128,  256, 0, stream>>>(ei, iws + I_DEG);
  k_scan   <<<1,   1024, 0, stream>>>(iws + I_DEG, iws + I_RP, iws + I_CUR);
  k_fill   <<<144,  256, 0, stream>>>(ei, iws + I_CUR, iws + I_EID);
  k_sort   <<<64,    64, 0, stream>>>(iws + I_RP, iws + I_EID);
  k_loopattr<<<256, 256, 0, stream>>>(eattr, iws + I_RP, iws + I_EID, ws + OFF_LP);

  k_proj   <<<512,  256, 0, stream>>>(W1, as1w, ad1w, ws + OFF_WS1, ws + OFF_WD1, 512, 512);
  k_proj   <<<2048, 256, 0, stream>>>(W2, as2w, ad2w, ws + OFF_WS2, ws + OFF_WD2, 2048, 2048);
  k_aeproj <<<16,   256, 0, stream>>>(We1, ae1w, ws + OFF_AE1, 512);
  k_aeproj <<<16,   256, 0, stream>>>(We2, ae2w, ws + OFF_AE2, 2048);
  k_wsplit<true, true><<<dim3(256, 8), 256, 0, stream>>>(Wout, 256, 0, 8192, woh, wol);   // fp16 [256][8192]

  // ---- layer 1 (bf16 3-term); epilogue writes x2 as fp16 hi/lo directly ----
  k_asad<false><<<4096, 256, 0, stream>>>(ws + OFF_X, nullptr, ws + OFF_WS1, ws + OFF_WD1, ws + OFF_AS1, ws + OFF_AD1, 512);
  k_edge      <<<144,  256, 0, stream>>>(eattr, ws + OFF_LP, ei, ws + OFF_AS1, ws + OFF_AD1, ws + OFF_AE1, ws + OFF_EB);
  k_softmax   <<<1024, 256, 0, stream>>>(iws + I_RP, iws + I_EID, ws + OFF_EB, ws + OFF_AL);
  k_agg1_split<<<4096, 256, 0, stream>>>(ws + OFF_X, ws + OFF_AL, iws + I_RP, iws + I_EID, ei, z1hi, z1lo);
  // X dead; wt1 overlays it
  k_wsplit<false, true><<<dim3(16, 64), 256, 0, stream>>>(W1, 2048, 0, 512, wt1h, wt1l);  // bf16 [2048][512]
  k_gemm2<512, false, false, 2, false, true, true><<<dim3(4, 32, 4), 256, 0, stream>>>(
      z1hi, z1lo, 2048, 512,  wt1h, wt1l, 512, 512*512,
      x2hi, x2lo, 2048, 512,  b1, 512);

  // ---- layer 2 attention (x2 = hi+lo fp16, reconstructed: near-exact) ----
  k_asad<true><<<4096, 256, 0, stream>>>(x2hi, x2lo, ws + OFF_WS2, ws + OFF_WD2, ws + OFF_AS2, ws + OFF_AD2, 2048);
  k_edge   <<<144,  256, 0, stream>>>(eattr, ws + OFF_LP, ei, ws + OFF_AS2, ws + OFF_AD2, ws + OFF_AE2, ws + OFF_EB);
  k_softmax<<<1024, 256, 0, stream>>>(iws + I_RP, iws + I_EID, ws + OFF_EB, ws + OFF_AL);

  // ---- layer 2 + fc, per head: H = x2@W2_h^T (fp16 MFMA), sparse agg of fp16 H, fp16 FC ----
  for (int h = 0; h < 4; ++h){
    k_wsplit<true, false><<<dim3(64, 64), 256, 0, stream>>>(W2, 8192, h*2048, 2048, whi, nullptr);
    k_gemm256 <<<dim3(8, 32), 512, 0, stream>>>(x2hi, x2lo, whi, Hb);
    k_agg2b   <<<4096, 256, 0, stream>>>(Hb, ws + OFF_AL, iws + I_RP, iws + I_EID, ei, x3, b2, h);
    if (h == 0)
      k_gemm2<512, true, true, 0, false, false, false><<<dim3(2, 32, 4), 256, 0, stream>>>(
          x3, x3, 2048, 512,  woh + (size_t)h*2048, wol + (size_t)h*2048, 8192, 512,
          ws + OFF_YP, nullptr, 256, (size_t)Nn*256,  nullptr, 0);
    else
      k_gemm2<512, true, true, 0, true, false, false><<<dim3(2, 32, 4), 256, 0, stream>>>(
          x3, x3, 2048, 512,  woh + (size_t)h*2048, wol + (size_t)h*2048, 8192, 512,
          ws + OFF_YP, nullptr, 256, (size_t)Nn*256,  nullptr, 0);
  }

  k_gsum<<<dim3(32, 8), 256, 0, stream>>>(ws + OFF_YP, bout, batch, ws + OFF_PART);
  k_gfin<<<8, 256, 0, stream>>>(ws + OFF_PART, batch, out);
}

// Round 16
// 695.413 us; speedup vs baseline: 1.0299x; 1.0003x over previous
//
#include <hip/hip_runtime.h>
#include <math.h>

constexpr int Nn  = 4096;
constexpr int Ne  = 32768;
constexpr int NEf = Ne + Nn;     // real edges + self loops

// ---------------- ws layout (float offsets) ----------------
// R0 [0..2097152)        X fp32 (prep/L1) -> wt1 hi/lo bf16 (L1 gemm) -> whi0 fp16 [2048][2048] (head loop)
// R1 [2097152..10485760) z1 hi/lo bf16 (L1) -> HA/HB fp16 [4096][2048] x2 (head loop) -> part fp32 (final)
// R2 [10485760..18874368) x2hi/x2lo fp16 [4096][2048]
// R3 [18874368..23068672) x3 fp16 [4096][2048] (head loop)
// R4 [23068672..25165824) whi1 fp16 [2048][2048]
// R5 [25165824..27262976) wtout hi/lo fp16 [256][8192]
// R6 [27262976..31457280) YP 4x [4096][256] fp32
constexpr size_t OFF_X    = 0;
constexpr size_t OFF_WT1H = 0;
constexpr size_t OFF_WT1L = 524288;
constexpr size_t OFF_Z1HI = 2097152;
constexpr size_t OFF_Z1LO = 6291456;
constexpr size_t OFF_HA   = 2097152;     // ushort region (fp16) [4096][2048]
constexpr size_t OFF_HB   = 6291456;     // ushort region (fp16) [4096][2048]
constexpr size_t OFF_PART = 2097152;     // fp32, overlays dead HA (final)
constexpr size_t OFF_X2HI = 10485760;    // ushort region
constexpr size_t OFF_X2LO = 14680064;    // ushort region
constexpr size_t OFF_X3   = 18874368;    // ushort region (fp16) [4096][2048]
constexpr size_t OFF_WHI1 = 23068672;    // ushort region [2048][2048] fp16
constexpr size_t OFF_WOH  = 25165824;    // ushort region [256][8192] fp16
constexpr size_t OFF_WOL  = 26214400;    // ushort region
constexpr size_t OFF_YP   = 27262976;
constexpr size_t OFF_LP  = 31457280;     // [N,16] self-loop edge attr
constexpr size_t OFF_WS1 = OFF_LP  + 65536;   // [512,4]
constexpr size_t OFF_WD1 = OFF_WS1 + 2048;    // [512,4]
constexpr size_t OFF_WS2 = OFF_WD1 + 2048;    // [2048,4]
constexpr size_t OFF_WD2 = OFF_WS2 + 8192;    // [2048,4]
constexpr size_t OFF_AE1 = OFF_WD2 + 8192;    // [16,4]
constexpr size_t OFF_AE2 = OFF_AE1 + 64;      // [16,4]
constexpr size_t OFF_AS1 = OFF_AE2 + 64;      // [N,4]
constexpr size_t OFF_AD1 = OFF_AS1 + 16384;
constexpr size_t OFF_AS2 = OFF_AD1 + 16384;
constexpr size_t OFF_AD2 = OFF_AS2 + 16384;
constexpr size_t OFF_EB  = OFF_AD2 + 16384;          // [Ef,4] logits
constexpr size_t OFF_AL  = OFF_EB  + (size_t)NEf*4;  // [Ef,4] alpha
constexpr size_t OFF_I   = OFF_AL  + (size_t)NEf*4;  // int region
constexpr size_t I_DEG = 0;       // [N]
constexpr size_t I_RP  = 4096;    // [N+1] (+pad)
constexpr size_t I_CUR = 8200;    // [N]
constexpr size_t I_EID = 12296;   // [Ef]
constexpr size_t WS_FLOATS = OFF_I + I_EID + (size_t)NEf + 64;

using bf16x8 = __bf16 __attribute__((ext_vector_type(8)));
using f16x8  = _Float16 __attribute__((ext_vector_type(8)));
using f32x4  = float __attribute__((ext_vector_type(4)));

__device__ __forceinline__ float wred64(float v){
#pragma unroll
  for (int o = 32; o > 0; o >>= 1) v += __shfl_down(v, o, 64);
  return v;
}
__device__ __forceinline__ float lrelu(float v, float s){ return v > 0.f ? v : s * v; }

__device__ __forceinline__ unsigned short f2bf(float x){  // RTNE
  unsigned int u = __float_as_uint(x);
  unsigned int r = (u + 0x7FFFu + ((u >> 16) & 1u)) >> 16;
  return (unsigned short)r;
}
__device__ __forceinline__ float bf2f(unsigned short h){
  return __uint_as_float((unsigned int)h << 16);
}
__device__ __forceinline__ void split2(float x, unsigned short& h, unsigned short& l){
  h = f2bf(x);
  l = f2bf(x - bf2f(h));
}
__device__ __forceinline__ unsigned short f2h(float x){
  _Float16 h = (_Float16)x;
  return __builtin_bit_cast(unsigned short, h);
}
__device__ __forceinline__ float h2f(unsigned short u){
  return (float)__builtin_bit_cast(_Float16, u);
}
__device__ __forceinline__ void split2h(float x, unsigned short& h, unsigned short& l){
  _Float16 hh = (_Float16)x;
  h = __builtin_bit_cast(unsigned short, hh);
  _Float16 ll = (_Float16)(x - (float)hh);
  l = __builtin_bit_cast(unsigned short, ll);
}
__device__ __forceinline__ void gload16(const void* g, void* l){
  __builtin_amdgcn_global_load_lds((const __attribute__((address_space(1))) void*)g,
                                   (__attribute__((address_space(3))) void*)l, 16, 0, 0);
}

// ---------------- small prep kernels ----------------
__global__ void k_concat(const float* __restrict__ xg, const float* __restrict__ ac,
                         const float* __restrict__ ti, float* __restrict__ x){
  int i = blockIdx.x * 256 + threadIdx.x;          // over N*512
  int n = i >> 9, c = i & 511;
  float v;
  if (c < 256)      v = xg[(size_t)n*256 + c];
  else if (c < 384) v = ac[(size_t)n*128 + (c-256)];
  else              v = ti[(size_t)n*128 + (c-384)];
  x[i] = v;
}

__global__ void k_count(const int* __restrict__ ei, int* __restrict__ deg){
  int e = blockIdx.x * 256 + threadIdx.x;
  if (e < Ne) atomicAdd(&deg[ei[Ne + e]], 1);
}

__global__ void k_scan(const int* __restrict__ deg, int* __restrict__ rowptr, int* __restrict__ cursor){
  __shared__ int sd[1024];
  int t = threadIdx.x;
  int v[4]; int s = 0;
#pragma unroll
  for (int i = 0; i < 4; i++){ v[i] = s; s += deg[t*4 + i] + 1; }   // +1 self loop
  sd[t] = s;
  __syncthreads();
  for (int off = 1; off < 1024; off <<= 1){
    int x = (t >= off) ? sd[t - off] : 0;
    __syncthreads();
    sd[t] += x;
    __syncthreads();
  }
  int base = (t == 0) ? 0 : sd[t - 1];
#pragma unroll
  for (int i = 0; i < 4; i++){ int rp = base + v[i]; rowptr[t*4 + i] = rp; cursor[t*4 + i] = rp; }
  if (t == 1023) rowptr[4096] = sd[1023];
}

__global__ void k_fill(const int* __restrict__ ei, int* __restrict__ cursor, int* __restrict__ eids){
  int e = blockIdx.x * 256 + threadIdx.x;
  if (e >= NEf) return;
  int d = (e < Ne) ? ei[Ne + e] : (e - Ne);
  int p = atomicAdd(&cursor[d], 1);
  eids[p] = e;
}

__global__ void k_sort(const int* __restrict__ rowptr, int* __restrict__ eids){
  int n = blockIdx.x * 64 + threadIdx.x;
  if (n >= Nn) return;
  int b = rowptr[n], e = rowptr[n + 1];
  for (int i = b + 1; i < e; i++){
    int key = eids[i]; int j = i - 1;
    while (j >= b && eids[j] > key){ eids[j+1] = eids[j]; j--; }
    eids[j+1] = key;
  }
}

__global__ void k_loopattr(const float* __restrict__ eattr, const int* __restrict__ rowptr,
                           const int* __restrict__ eids, float* __restrict__ lp){
  int idx = blockIdx.x * 256 + threadIdx.x;        // N*16
  int n = idx >> 4, a = idx & 15;
  if (n >= Nn) return;
  int b = rowptr[n], e = rowptr[n + 1];
  float s = 0.f; int cnt = 0;
  for (int j = b; j < e; ++j){
    int id = eids[j];
    if (id < Ne){ s += eattr[(size_t)id*16 + a]; cnt++; }
  }
  lp[(size_t)n*16 + a] = s / fmaxf((float)cnt, 1.f);
}

// Ws[k,h] = sum_c W[k, h*C+c]*a_s[h,c] ; Wd likewise.
__global__ void k_proj(const float* __restrict__ W, const float* __restrict__ a_s,
                       const float* __restrict__ a_d, float* __restrict__ Ws,
                       float* __restrict__ Wd, int K, int C){
  int gid = blockIdx.x * 256 + threadIdx.x;
  int wave = gid >> 6, lane = gid & 63;
  int h = wave & 3, k = wave >> 2;
  if (k >= K) return;
  const float* wrow = W + (size_t)k * (4*C) + (size_t)h * C;
  const float* ar = a_s + (size_t)h * C;
  const float* dr = a_d + (size_t)h * C;
  float ps = 0.f, pd = 0.f;
  for (int c = lane; c < C; c += 64){ float w = wrow[c]; ps += w * ar[c]; pd += w * dr[c]; }
  ps = wred64(ps); pd = wred64(pd);
  if (lane == 0){ Ws[k*4 + h] = ps; Wd[k*4 + h] = pd; }
}

// one wave per (k,h): outp[k*4+h] = dot(We[k, h*C:(h+1)*C], ae[h,:])
__global__ void k_aeproj(const float* __restrict__ We, const float* __restrict__ ae,
                         float* __restrict__ outp, int C){
  int gid = blockIdx.x * 256 + threadIdx.x;
  int wave = gid >> 6, lane = gid & 63;
  int h = wave & 3, k = wave >> 2;
  if (k >= 16) return;
  const float* wrow = We + (size_t)k * (4*C) + (size_t)h * C;
  const float* ar = ae + (size_t)h * C;
  float s = 0.f;
  for (int c = lane; c < C; c += 64) s += wrow[c] * ar[c];
  s = wred64(s);
  if (lane == 0) outp[k*4 + h] = s;
}

// as[n,h], ad[n,h] = x[n,:] @ Ws/Wd. Block per node.
template<bool HALF>
__global__ __launch_bounds__(256) void k_asad(const void* __restrict__ xp, const void* __restrict__ xlp,
                      const float* __restrict__ Ws,
                      const float* __restrict__ Wd, float* __restrict__ as_,
                      float* __restrict__ ad_, int D){
  int n = blockIdx.x, t = threadIdx.x;
  float p[8] = {0,0,0,0,0,0,0,0};
  if (HALF){
    const unsigned short* rh = (const unsigned short*)xp + (size_t)n * D;
    const unsigned short* rl = (const unsigned short*)xlp + (size_t)n * D;
    for (int c = t; c < D; c += 256){
      float xv = h2f(rh[c]) + h2f(rl[c]);
      float4 ws4 = *(const float4*)&Ws[c*4];
      float4 wd4 = *(const float4*)&Wd[c*4];
      p[0] += xv * ws4.x; p[1] += xv * ws4.y; p[2] += xv * ws4.z; p[3] += xv * ws4.w;
      p[4] += xv * wd4.x; p[5] += xv * wd4.y; p[6] += xv * wd4.z; p[7] += xv * wd4.w;
    }
  } else {
    const float* row = (const float*)xp + (size_t)n * D;
    for (int c = t; c < D; c += 256){
      float xv = row[c];
      float4 ws4 = *(const float4*)&Ws[c*4];
      float4 wd4 = *(const float4*)&Wd[c*4];
      p[0] += xv * ws4.x; p[1] += xv * ws4.y; p[2] += xv * ws4.z; p[3] += xv * ws4.w;
      p[4] += xv * wd4.x; p[5] += xv * wd4.y; p[6] += xv * wd4.z; p[7] += xv * wd4.w;
    }
  }
  __shared__ float sm[4][8];
  int lane = t & 63, wid = t >> 6;
#pragma unroll
  for (int q = 0; q < 8; q++){
    float v = wred64(p[q]);
    if (lane == 0) sm[wid][q] = v;
  }
  __syncthreads();
  if (t < 8){
    float s = sm[0][t] + sm[1][t] + sm[2][t] + sm[3][t];
    if (t < 4) as_[(size_t)n*4 + t] = s;
    else       ad_[(size_t)n*4 + (t-4)] = s;
  }
}

__global__ void k_edge(const float* __restrict__ eattr, const float* __restrict__ lp,
                       const int* __restrict__ ei, const float* __restrict__ as_,
                       const float* __restrict__ ad_, const float* __restrict__ aep,
                       float* __restrict__ ebuf){
  int e = blockIdx.x * 256 + threadIdx.x;
  if (e >= NEf) return;
  int s, d; const float* ea;
  if (e < Ne){ s = ei[e]; d = ei[Ne + e]; ea = eattr + (size_t)e * 16; }
  else { s = e - Ne; d = e - Ne; ea = lp + (size_t)(e - Ne) * 16; }
  float eav[16];
#pragma unroll
  for (int k = 0; k < 16; k++) eav[k] = ea[k];
#pragma unroll
  for (int h = 0; h < 4; h++){
    float v = as_[(size_t)s*4 + h] + ad_[(size_t)d*4 + h];
#pragma unroll
    for (int k = 0; k < 16; k++) v += eav[k] * aep[k*4 + h];
    ebuf[(size_t)e*4 + h] = lrelu(v, 0.2f);
  }
}

// wave-per-node softmax: 4 waves/block, 1024 blocks.
__global__ __launch_bounds__(256) void k_softmax(const int* __restrict__ rowptr, const int* __restrict__ eids,
                          const float* __restrict__ ebuf, float* __restrict__ alpha){
  const int wid = threadIdx.x >> 6, lane = threadIdx.x & 63;
  const int n = blockIdx.x * 4 + wid;
  const int b = rowptr[n], e = rowptr[n + 1];
  float4 m = {-1e30f, -1e30f, -1e30f, -1e30f};
  for (int j = b + lane; j < e; j += 64){
    float4 ev = *(const float4*)&ebuf[(size_t)eids[j]*4];
    m.x = fmaxf(m.x, ev.x); m.y = fmaxf(m.y, ev.y);
    m.z = fmaxf(m.z, ev.z); m.w = fmaxf(m.w, ev.w);
  }
#pragma unroll
  for (int o = 32; o > 0; o >>= 1){
    m.x = fmaxf(m.x, __shfl_xor(m.x, o, 64));
    m.y = fmaxf(m.y, __shfl_xor(m.y, o, 64));
    m.z = fmaxf(m.z, __shfl_xor(m.z, o, 64));
    m.w = fmaxf(m.w, __shfl_xor(m.w, o, 64));
  }
  float4 s = {0.f, 0.f, 0.f, 0.f};
  for (int j = b + lane; j < e; j += 64){
    int eid = eids[j];
    float4 ev = *(const float4*)&ebuf[(size_t)eid*4];
    float4 ex = { expf(ev.x - m.x), expf(ev.y - m.y), expf(ev.z - m.z), expf(ev.w - m.w) };
    *(float4*)&alpha[(size_t)eid*4] = ex;
    s.x += ex.x; s.y += ex.y; s.z += ex.z; s.w += ex.w;
  }
#pragma unroll
  for (int o = 32; o > 0; o >>= 1){
    s.x += __shfl_xor(s.x, o, 64);
    s.y += __shfl_xor(s.y, o, 64);
    s.z += __shfl_xor(s.z, o, 64);
    s.w += __shfl_xor(s.w, o, 64);
  }
  float4 r = { 1.f/s.x, 1.f/s.y, 1.f/s.z, 1.f/s.w };
  for (int j = b + lane; j < e; j += 64){
    int eid = eids[j];
    float4 av = *(const float4*)&alpha[(size_t)eid*4];
    av.x *= r.x; av.y *= r.y; av.z *= r.z; av.w *= r.w;
    *(float4*)&alpha[(size_t)eid*4] = av;
  }
}

// z1[n, h*512+c] = sum_e alpha[e,h] * x[src(e),c], bf16 hi/lo split out.
__global__ __launch_bounds__(256) void k_agg1_split(const float* __restrict__ x, const float* __restrict__ alpha,
                      const int* __restrict__ rowptr, const int* __restrict__ eids,
                      const int* __restrict__ ei, unsigned short* __restrict__ z1hi,
                      unsigned short* __restrict__ z1lo){
  __shared__ float4 sal[128];
  __shared__ int    ssrc[128];
  int n = blockIdx.x, t = threadIdx.x;
  float2 a0 = {0,0}, a1 = {0,0}, a2 = {0,0}, a3 = {0,0};
  int b = rowptr[n], e = rowptr[n + 1];
  for (int c0 = b; c0 < e; c0 += 128){
    int cnt = min(e - c0, 128);
    __syncthreads();
    if (t < cnt){
      int eid = eids[c0 + t];
      ssrc[t] = (eid < Ne) ? ei[eid] : (eid - Ne);
      sal[t]  = *(const float4*)&alpha[(size_t)eid*4];
    }
    __syncthreads();
    for (int j = 0; j < cnt; ++j){
      float4 av = sal[j];
      float2 xv = *(const float2*)&x[(size_t)ssrc[j]*512 + t*2];
      a0.x += av.x*xv.x; a0.y += av.x*xv.y;
      a1.x += av.y*xv.x; a1.y += av.y*xv.y;
      a2.x += av.z*xv.x; a2.y += av.z*xv.y;
      a3.x += av.w*xv.x; a3.y += av.w*xv.y;
    }
  }
  size_t base = (size_t)n*2048 + t*2;
  float2 av[4] = {a0, a1, a2, a3};
#pragma unroll
  for (int h = 0; h < 4; h++){
    ushort2 hh, ll;
    split2(av[h].x, hh.x, ll.x);
    split2(av[h].y, hh.y, ll.y);
    *(ushort2*)&z1hi[base + h*512] = hh;
    *(ushort2*)&z1lo[base + h*512] = ll;
  }
}

// x3[n,:] = lrelu( sum_e alpha[e,h]*H[src,:] + b2_h, 0.01 ), fp16 in/out. Block per dst node.
__global__ __launch_bounds__(256) void k_agg2b(const unsigned short* __restrict__ H,
                      const float* __restrict__ alpha,
                      const int* __restrict__ rowptr, const int* __restrict__ eids,
                      const int* __restrict__ ei, unsigned short* __restrict__ x3,
                      const float* __restrict__ b2, int h){
  __shared__ float sal[128];
  __shared__ int   ssrc[128];
  int n = blockIdx.x, t = threadIdx.x;
  float acc[8] = {0,0,0,0,0,0,0,0};
  int b = rowptr[n], e = rowptr[n + 1];
  for (int c0 = b; c0 < e; c0 += 128){
    int cnt = min(e - c0, 128);
    __syncthreads();
    if (t < cnt){
      int eid = eids[c0 + t];
      ssrc[t] = (eid < Ne) ? ei[eid] : (eid - Ne);
      sal[t]  = alpha[(size_t)eid*4 + h];
    }
    __syncthreads();
    for (int j = 0; j < cnt; ++j){
      float a = sal[j];
      f16x8 hv = *(const f16x8*)&H[(size_t)ssrc[j]*2048 + t*8];
#pragma unroll
      for (int q = 0; q < 8; q++) acc[q] += a * (float)hv[q];
    }
  }
  const float* bb = b2 + (size_t)h*2048 + t*8;
  ushort4 o0, o1;
  float4 b0 = *(const float4*)bb;
  float4 b1 = *(const float4*)(bb + 4);
  o0.x = f2h(lrelu(acc[0] + b0.x, 0.01f)); o0.y = f2h(lrelu(acc[1] + b0.y, 0.01f));
  o0.z = f2h(lrelu(acc[2] + b0.z, 0.01f)); o0.w = f2h(lrelu(acc[3] + b0.w, 0.01f));
  o1.x = f2h(lrelu(acc[4] + b1.x, 0.01f)); o1.y = f2h(lrelu(acc[5] + b1.y, 0.01f));
  o1.z = f2h(lrelu(acc[6] + b1.z, 0.01f)); o1.w = f2h(lrelu(acc[7] + b1.w, 0.01f));
  size_t base = (size_t)n*2048 + t*8;
  *(ushort4*)&x3[base]     = o0;
  *(ushort4*)&x3[base + 4] = o1;
}

// transpose + split: out[col][k] = split(W[k][coloff+col]); out stride K.
template<bool HALF, bool STORELO>
__global__ __launch_bounds__(256) void k_wsplit(const float* __restrict__ W, int ldw, int coloff, int K,
                       unsigned short* __restrict__ whi, unsigned short* __restrict__ wlo){
  __shared__ float tile[32][33];
  int bk = blockIdx.x * 32, bn = blockIdx.y * 32;
  int tx = threadIdx.x & 31, ty = threadIdx.x >> 5;
#pragma unroll
  for (int i = 0; i < 4; i++){
    int k = bk + ty + i*8;
    tile[ty + i*8][tx] = W[(size_t)k*ldw + coloff + bn + tx];
  }
  __syncthreads();
#pragma unroll
  for (int i = 0; i < 4; i++){
    int n = bn + ty + i*8;
    float v = tile[tx][ty + i*8];
    unsigned short hh, ll;
    if (HALF) split2h(v, hh, ll); else split2(v, hh, ll);
    whi[(size_t)n*K + bk + tx] = hh;
    if (STORELO) wlo[(size_t)n*K + bk + tx] = ll;
  }
}

// W2 head-pair transpose+fp16 (z = head within pair): out[col][k] = fp16(W2[k][(h0+z)*2048+col])
__global__ __launch_bounds__(256) void k_wsplitW2(const float* __restrict__ W2, int h0,
                       unsigned short* __restrict__ w0, unsigned short* __restrict__ w1){
  __shared__ float tile[32][33];
  unsigned short* outp = blockIdx.z ? w1 : w0;
  const int coloff = (h0 + (int)blockIdx.z) * 2048;
  int bk = blockIdx.x * 32, bn = blockIdx.y * 32;
  int tx = threadIdx.x & 31, ty = threadIdx.x >> 5;
#pragma unroll
  for (int i = 0; i < 4; i++){
    int k = bk + ty + i*8;
    tile[ty + i*8][tx] = W2[(size_t)k*8192 + coloff + bn + tx];
  }
  __syncthreads();
#pragma unroll
  for (int i = 0; i < 4; i++){
    int n = bn + ty + i*8;
    outp[(size_t)n*2048 + bk + tx] = f2h(tile[tx][ty + i*8]);
  }
}

// ---------------- L2 dense GEMM: r15 register-pipelined, z = head-pair (2 heads/launch) ----------------
// H[z][4096][2048] = x2 x W2h(z)^T; fp16 2-term C = Ah*Bh + Al*Bh.
__global__ __launch_bounds__(512) void k_gemm256(
    const unsigned short* __restrict__ Ah, const unsigned short* __restrict__ Al,
    const unsigned short* __restrict__ Bh0, const unsigned short* __restrict__ Bh1,
    unsigned short* __restrict__ C0, unsigned short* __restrict__ C1)
{
  __shared__ __align__(16) unsigned short lds[49152];   // 3 x (A 8192 + B 8192) ushorts
  const int t = threadIdx.x;
  const unsigned short* Bh = blockIdx.z ? Bh1 : Bh0;
  unsigned short* Cout = blockIdx.z ? C1 : C0;
  const int bid = blockIdx.y * 8 + blockIdx.x;
  const int sbid = (bid & 7) * 32 + (bid >> 3);         // XCD-chunked swizzle
  const int brow = (sbid >> 3) * 128, bcol = (sbid & 7) * 256;
  const int w = t >> 6, lane = t & 63;
  const int wm = (w >> 2) * 64, wn = (w & 3) * 64;
  constexpr int BUF = 16384, BOFF = 8192;   // ushorts

  const int asr = t >> 3;
  const int ascc = (t & 7) ^ (asr & 7);
  const unsigned short* asrc = (ascc < 4 ? Ah : Al) + (size_t)(brow + asr)*2048 + (size_t)(ascc & 3)*8;
  const int bsr = t >> 2;
  const int bscc = (t & 3) ^ ((bsr >> 1) & 3);
  const unsigned short* bsrc = Bh + (size_t)(bcol + bsr)*2048 + (size_t)bscc*8;
  const int adst = w * 512;
  const int bdst = BOFF + w * 512;

  const int fr = lane & 15, kc = lane >> 4;
  const int aswz = (kc ^ (lane & 7)) * 8;
  const int bswz = (kc ^ ((lane >> 1) & 3)) * 8;
  int aoff[4], boff[4];
#pragma unroll
  for (int m = 0; m < 4; m++) aoff[m] = (wm + m*16 + fr)*64 + aswz;
#pragma unroll
  for (int n = 0; n < 4; n++) boff[n] = BOFF + (wn + n*16 + fr)*32 + bswz;

  f32x4 acc[4][4];
#pragma unroll
  for (int m = 0; m < 4; m++)
#pragma unroll
    for (int n = 0; n < 4; n++) acc[m][n] = f32x4{0.f, 0.f, 0.f, 0.f};

  f16x8 ahA[4], alA[4], bfA[4], ahB[4], alB[4], bfB[4];

  // prologue: stage tiles 0,1,2; vmcnt(4) => tiles 0,1 landed.
#pragma unroll
  for (int tl = 0; tl < 3; ++tl){
    const int bb = tl * BUF;
    const size_t ko = (size_t)tl * 32;
    gload16(asrc + ko,                    &lds[bb + adst]);
    gload16(asrc + (size_t)64*2048 + ko,  &lds[bb + 4096 + adst]);
    gload16(bsrc + ko,                    &lds[bb + bdst]);
    gload16(bsrc + (size_t)128*2048 + ko, &lds[bb + 4096 + bdst]);
  }
  asm volatile("s_waitcnt vmcnt(4)" ::: "memory");
  __builtin_amdgcn_s_barrier();
  __builtin_amdgcn_sched_barrier(0);
#pragma unroll
  for (int m = 0; m < 4; m++){
    ahA[m] = *(const f16x8*)&lds[aoff[m]];
    alA[m] = *(const f16x8*)&lds[aoff[m] ^ 32];
  }
#pragma unroll
  for (int n = 0; n < 4; n++) bfA[n] = *(const f16x8*)&lds[boff[n]];
  asm volatile("s_waitcnt lgkmcnt(0)" ::: "memory");
  __builtin_amdgcn_sched_barrier(0);

  auto step = [&](int kt_, f16x8 (&ahC)[4], f16x8 (&alC)[4], f16x8 (&bfC)[4],
                          f16x8 (&ahN)[4], f16x8 (&alN)[4], f16x8 (&bfN)[4]){
    if (kt_ + 3 < 64){
      const int nbo = ((kt_ + 3) % 3) * BUF;
      const size_t nko = (size_t)(kt_ + 3) * 32;
      gload16(asrc + nko,                    &lds[nbo + adst]);
      gload16(asrc + (size_t)64*2048 + nko,  &lds[nbo + 4096 + adst]);
      gload16(bsrc + nko,                    &lds[nbo + bdst]);
      gload16(bsrc + (size_t)128*2048 + nko, &lds[nbo + 4096 + bdst]);
    }
    if (kt_ + 1 < 64){
      const int nxb = ((kt_ + 1) % 3) * BUF;
#pragma unroll
      for (int m = 0; m < 4; m++){
        ahN[m] = *(const f16x8*)&lds[nxb + aoff[m]];
        alN[m] = *(const f16x8*)&lds[nxb + (aoff[m] ^ 32)];
      }
#pragma unroll
      for (int n = 0; n < 4; n++) bfN[n] = *(const f16x8*)&lds[nxb + boff[n]];
    }
    __builtin_amdgcn_s_setprio(1);
#pragma unroll
    for (int n = 0; n < 4; n++){
#pragma unroll
      for (int m = 0; m < 4; m++) acc[m][n] = __builtin_amdgcn_mfma_f32_16x16x32_f16(ahC[m], bfC[n], acc[m][n], 0, 0, 0);
#pragma unroll
      for (int m = 0; m < 4; m++) acc[m][n] = __builtin_amdgcn_mfma_f32_16x16x32_f16(alC[m], bfC[n], acc[m][n], 0, 0, 0);
    }
    __builtin_amdgcn_s_setprio(0);
    asm volatile("s_waitcnt lgkmcnt(0)" ::: "memory");
    if (kt_ + 3 < 64) asm volatile("s_waitcnt vmcnt(4)" ::: "memory");
    else              asm volatile("s_waitcnt vmcnt(0)" ::: "memory");
    __builtin_amdgcn_s_barrier();
    __builtin_amdgcn_sched_barrier(0);
  };

  for (int kt = 0; kt < 64; kt += 2){
    step(kt,     ahA, alA, bfA, ahB, alB, bfB);
    step(kt + 1, ahB, alB, bfB, ahA, alA, bfA);
  }

#pragma unroll
  for (int m = 0; m < 4; m++){
    const int row0 = brow + wm + m*16 + kc*4;
#pragma unroll
    for (int n = 0; n < 4; n++){
      const int col = bcol + wn + n*16 + fr;
#pragma unroll
      for (int r = 0; r < 4; r++)
        Cout[(size_t)(row0 + r)*2048 + col] = f2h(acc[m][n][r]);
    }
  }
}

// ---------------- MFMA GEMM (128x128): bf16 3-term, or fp16 exact-A 2-term ----------------
// OUTMODE: 0 = fp32 (+BETA1), 1 = bf16, 2 = fp16 hi/lo split to Cout/Cout2
template<int KLEN, bool EXACTA, bool HALF, int OUTMODE, bool BETA1, bool ACT, bool HASBIAS>
__global__ __launch_bounds__(256) void k_gemm2(
    const unsigned short* __restrict__ Ah, const unsigned short* __restrict__ Al, int lda, size_t az,
    const unsigned short* __restrict__ Bh, const unsigned short* __restrict__ Bl, int ldb, size_t bz,
    void* __restrict__ Cout, void* __restrict__ Cout2, int ldc, size_t cz,
    const float* __restrict__ bias, size_t biasz)
{
  __shared__ unsigned short lds[16384];   // A: [0,8192) ushorts, B: [8192,16384)
  const int t = threadIdx.x;
  const int z = blockIdx.z;
  const int brow = blockIdx.y * 128, bcol = blockIdx.x * 128;
  const int wid = t >> 6, lane = t & 63;
  const int wm = (wid >> 1) * 64, wn = (wid & 1) * 64;

  const int sr = t >> 3, sc = t & 7;
  const int scc = sc ^ (sr & 7);
  const unsigned short* asrc = (scc < 4 ? Ah : Al) + (size_t)(brow + sr)*lda + (size_t)z*az + (size_t)(scc & 3)*8;
  const unsigned short* bsrc = (scc < 4 ? Bh : Bl) + (size_t)(bcol + sr)*ldb + (size_t)z*bz + (size_t)(scc & 3)*8;
  unsigned short* adst = &lds[(size_t)wid * 512];
  unsigned short* bdst = &lds[8192 + (size_t)wid * 512];

  const int fr = lane & 15, kc = lane >> 4;
  const int swz = ((kc ^ (lane & 7)) << 3);
  int aoff[4], boff[4];
#pragma unroll
  for (int m = 0; m < 4; m++) aoff[m] = (wm + m*16 + fr)*64 + swz;
#pragma unroll
  for (int n = 0; n < 4; n++) boff[n] = 8192 + (wn + n*16 + fr)*64 + swz;

  f32x4 acc[4][4];
#pragma unroll
  for (int m = 0; m < 4; m++)
#pragma unroll
    for (int n = 0; n < 4; n++) acc[m][n] = f32x4{0.f, 0.f, 0.f, 0.f};

  for (int kt = 0; kt < KLEN/32; ++kt){
    const size_t ko = (size_t)kt * 32;
#pragma unroll
    for (int i = 0; i < 4; i++){
      gload16(asrc + (size_t)i*32*lda + ko, adst + i*2048);
      gload16(bsrc + (size_t)i*32*ldb + ko, bdst + i*2048);
    }
    __syncthreads();

    if (HALF){
      f16x8 ah[4], bh[4], bl[4];
#pragma unroll
      for (int m = 0; m < 4; m++) ah[m] = *(const f16x8*)&lds[aoff[m]];
#pragma unroll
      for (int n = 0; n < 4; n++){
        bh[n] = *(const f16x8*)&lds[boff[n]];
        bl[n] = *(const f16x8*)&lds[boff[n] ^ 32];
      }
#pragma unroll
      for (int m = 0; m < 4; m++)
#pragma unroll
        for (int n = 0; n < 4; n++){
          acc[m][n] = __builtin_amdgcn_mfma_f32_16x16x32_f16(ah[m], bh[n], acc[m][n], 0, 0, 0);
          acc[m][n] = __builtin_amdgcn_mfma_f32_16x16x32_f16(ah[m], bl[n], acc[m][n], 0, 0, 0);
        }
    } else {
      bf16x8 ah[4], al[4], bh[4], bl[4];
#pragma unroll
      for (int m = 0; m < 4; m++){
        ah[m] = *(const bf16x8*)&lds[aoff[m]];
        if (!EXACTA) al[m] = *(const bf16x8*)&lds[aoff[m] ^ 32];
      }
#pragma unroll
      for (int n = 0; n < 4; n++){
        bh[n] = *(const bf16x8*)&lds[boff[n]];
        bl[n] = *(const bf16x8*)&lds[boff[n] ^ 32];
      }
#pragma unroll
      for (int m = 0; m < 4; m++)
#pragma unroll
        for (int n = 0; n < 4; n++){
          acc[m][n] = __builtin_amdgcn_mfma_f32_16x16x32_bf16(ah[m], bh[n], acc[m][n], 0, 0, 0);
          acc[m][n] = __builtin_amdgcn_mfma_f32_16x16x32_bf16(ah[m], bl[n], acc[m][n], 0, 0, 0);
          if (!EXACTA)
            acc[m][n] = __builtin_amdgcn_mfma_f32_16x16x32_bf16(al[m], bh[n], acc[m][n], 0, 0, 0);
        }
    }
    __syncthreads();
  }

  float bv[4] = {0.f, 0.f, 0.f, 0.f};
  if (HASBIAS){
#pragma unroll
    for (int n = 0; n < 4; n++) bv[n] = bias[(size_t)z*biasz + bcol + wn + n*16 + fr];
  }
  float* Cf = (float*)Cout + (size_t)z*cz;
  unsigned short* Cb = (unsigned short*)Cout + (size_t)z*cz;
  unsigned short* Cl = (unsigned short*)Cout2 + (size_t)z*cz;
#pragma unroll
  for (int m = 0; m < 4; m++){
    const int row0 = brow + wm + m*16 + kc*4;
#pragma unroll
    for (int n = 0; n < 4; n++){
      const int col = bcol + wn + n*16 + fr;
#pragma unroll
      for (int r = 0; r < 4; r++){
        float v = acc[m][n][r] + bv[n];
        if (ACT) v = lrelu(v, 0.01f);
        size_t idx = (size_t)(row0 + r)*ldc + col;
        if (OUTMODE == 0){
          float* cp = &Cf[idx];
          if (BETA1) v += *cp;
          *cp = v;
        } else if (OUTMODE == 1){
          Cb[idx] = f2bf(v);
        } else {
          unsigned short hh, ll; split2h(v, hh, ll);
          Cb[idx] = hh; Cl[idx] = ll;
        }
      }
    }
  }
}

// stage 1: per (slice, graph) partial sums over stride-32 node slices
__global__ void k_gsum(const float* __restrict__ yp, const float* __restrict__ bout,
                       const int* __restrict__ batch, float* __restrict__ part){
  const int s = blockIdx.x, g = blockIdx.y, t = threadIdx.x;
  __shared__ int sb[2];
  if (t < 2){
    int key = g + t, lo = 0, hi = Nn;
    while (lo < hi){ int mid = (lo + hi) >> 1; if (batch[mid] < key) lo = mid + 1; else hi = mid; }
    sb[t] = lo;
  }
  __syncthreads();
  const int b = sb[0], e = sb[1];
  const size_t P = (size_t)Nn * 256;
  float acc = 0.f;
  float bt = bout[t];
  for (int n = b + s; n < e; n += 32){
    size_t i = (size_t)n*256 + t;
    float v = yp[i] + yp[P + i] + yp[2*P + i] + yp[3*P + i] + bt;
    acc += lrelu(v, 0.01f);
  }
  part[(size_t)(g*32 + s)*256 + t] = acc;
}

// stage 2: sum 32 slices, divide by count
__global__ void k_gfin(const float* __restrict__ part, const int* __restrict__ batch,
                       float* __restrict__ out){
  const int g = blockIdx.x, t = threadIdx.x;
  __shared__ int sb[2];
  if (t < 2){
    int key = g + t, lo = 0, hi = Nn;
    while (lo < hi){ int mid = (lo + hi) >> 1; if (batch[mid] < key) lo = mid + 1; else hi = mid; }
    sb[t] = lo;
  }
  __syncthreads();
  const int cnt = sb[1] - sb[0];
  float s = 0.f;
#pragma unroll
  for (int k = 0; k < 32; k++) s += part[(size_t)(g*32 + k)*256 + t];
  out[g*256 + t] = s / fmaxf((float)cnt, 1.f);
}

// ---------------- launch ----------------
extern "C" void kernel_launch(void* const* d_in, const int* in_sizes, int n_in,
                              void* d_out, int out_size, void* d_ws, size_t ws_size,
                              hipStream_t stream){
  const float* xg    = (const float*)d_in[0];
  const float* ac    = (const float*)d_in[1];
  const float* ti    = (const float*)d_in[2];
  const float* eattr = (const float*)d_in[3];
  const int*   ei    = (const int*)  d_in[4];
  const int*   batch = (const int*)  d_in[5];
  const float* W1    = (const float*)d_in[6];
  const float* as1w  = (const float*)d_in[7];
  const float* ad1w  = (const float*)d_in[8];
  const float* ae1w  = (const float*)d_in[9];
  const float* We1   = (const float*)d_in[10];
  const float* b1    = (const float*)d_in[11];
  const float* W2    = (const float*)d_in[12];
  const float* as2w  = (const float*)d_in[13];
  const float* ad2w  = (const float*)d_in[14];
  const float* ae2w  = (const float*)d_in[15];
  const float* We2   = (const float*)d_in[16];
  const float* b2    = (const float*)d_in[17];
  const float* Wout  = (const float*)d_in[18];
  const float* bout  = (const float*)d_in[19];
  float* out = (float*)d_out;
  float* ws  = (float*)d_ws;
  if (ws_size < WS_FLOATS * sizeof(float)) return;
  int* iws = (int*)(ws + OFF_I);

  unsigned short* z1hi = (unsigned short*)(ws + OFF_Z1HI);
  unsigned short* z1lo = (unsigned short*)(ws + OFF_Z1LO);
  unsigned short* wt1h = (unsigned short*)(ws + OFF_WT1H);
  unsigned short* wt1l = (unsigned short*)(ws + OFF_WT1L);
  unsigned short* x2hi = (unsigned short*)(ws + OFF_X2HI);
  unsigned short* x2lo = (unsigned short*)(ws + OFF_X2LO);
  unsigned short* whi0 = (unsigned short*)(ws + OFF_X);
  unsigned short* whi1 = (unsigned short*)(ws + OFF_WHI1);
  unsigned short* woh  = (unsigned short*)(ws + OFF_WOH);
  unsigned short* wol  = (unsigned short*)(ws + OFF_WOL);
  unsigned short* HA   = (unsigned short*)(ws + OFF_HA);
  unsigned short* HB   = (unsigned short*)(ws + OFF_HB);
  unsigned short* x3   = (unsigned short*)(ws + OFF_X3);

  hipMemsetAsync(iws + I_DEG, 0, Nn * sizeof(int), stream);
  k_concat <<<8192, 256, 0, stream>>>(xg, ac, ti, ws + OFF_X);
  k_count  <<<128,  256, 0, stream>>>(ei, iws + I_DEG);
  k_scan   <<<1,   1024, 0, stream>>>(iws + I_DEG, iws + I_RP, iws + I_CUR);
  k_fill   <<<144,  256, 0, stream>>>(ei, iws + I_CUR, iws + I_EID);
  k_sort   <<<64,    64, 0, stream>>>(iws + I_RP, iws + I_EID);
  k_loopattr<<<256, 256, 0, stream>>>(eattr, iws + I_RP, iws + I_EID, ws + OFF_LP);

  k_proj   <<<512,  256, 0, stream>>>(W1, as1w, ad1w, ws + OFF_WS1, ws + OFF_WD1, 512, 512);
  k_proj   <<<2048, 256, 0, stream>>>(W2, as2w, ad2w, ws + OFF_WS2, ws + OFF_WD2, 2048, 2048);
  k_aeproj <<<16,   256, 0, stream>>>(We1, ae1w, ws + OFF_AE1, 512);
  k_aeproj <<<16,   256, 0, stream>>>(We2, ae2w, ws + OFF_AE2, 2048);
  k_wsplit<true, true><<<dim3(256, 8), 256, 0, stream>>>(Wout, 256, 0, 8192, woh, wol);   // fp16 [256][8192]

  // ---- layer 1 (bf16 3-term); epilogue writes x2 as fp16 hi/lo directly ----
  k_asad<false><<<4096, 256, 0, stream>>>(ws + OFF_X, nullptr, ws + OFF_WS1, ws + OFF_WD1, ws + OFF_AS1, ws + OFF_AD1, 512);
  k_edge      <<<144,  256, 0, stream>>>(eattr, ws + OFF_LP, ei, ws + OFF_AS1, ws + OFF_AD1, ws + OFF_AE1, ws + OFF_EB);
  k_softmax   <<<1024, 256, 0, stream>>>(iws + I_RP, iws + I_EID, ws + OFF_EB, ws + OFF_AL);
  k_agg1_split<<<4096, 256, 0, stream>>>(ws + OFF_X, ws + OFF_AL, iws + I_RP, iws + I_EID, ei, z1hi, z1lo);
  // X dead; wt1 overlays it
  k_wsplit<false, true><<<dim3(16, 64), 256, 0, stream>>>(W1, 2048, 0, 512, wt1h, wt1l);  // bf16 [2048][512]
  k_gemm2<512, false, false, 2, false, true, true><<<dim3(4, 32, 4), 256, 0, stream>>>(
      z1hi, z1lo, 2048, 512,  wt1h, wt1l, 512, 512*512,
      x2hi, x2lo, 2048, 512,  b1, 512);

  // ---- layer 2 attention (x2 = hi+lo fp16, reconstructed: near-exact) ----
  k_asad<true><<<4096, 256, 0, stream>>>(x2hi, x2lo, ws + OFF_WS2, ws + OFF_WD2, ws + OFF_AS2, ws + OFF_AD2, 2048);
  k_edge   <<<144,  256, 0, stream>>>(eattr, ws + OFF_LP, ei, ws + OFF_AS2, ws + OFF_AD2, ws + OFF_AE2, ws + OFF_EB);
  k_softmax<<<1024, 256, 0, stream>>>(iws + I_RP, iws + I_EID, ws + OFF_EB, ws + OFF_AL);
  // z1 dead from here: HA/HB overlay R1

  // ---- layer 2 + fc, per head PAIR: H(2 heads) = x2@W2^T (one z=2 dispatch), then agg+FC per head ----
  for (int hp = 0; hp < 2; ++hp){
    k_wsplitW2<<<dim3(64, 64, 2), 256, 0, stream>>>(W2, hp*2, whi0, whi1);
    k_gemm256 <<<dim3(8, 32, 2), 512, 0, stream>>>(x2hi, x2lo, whi0, whi1, HA, HB);
    for (int j = 0; j < 2; ++j){
      const int h = hp*2 + j;
      k_agg2b<<<4096, 256, 0, stream>>>(j ? HB : HA, ws + OFF_AL, iws + I_RP, iws + I_EID, ei, x3, b2, h);
      if (h == 0)
        k_gemm2<512, true, true, 0, false, false, false><<<dim3(2, 32, 4), 256, 0, stream>>>(
            x3, x3, 2048, 512,  woh + (size_t)h*2048, wol + (size_t)h*2048, 8192, 512,
            ws + OFF_YP, nullptr, 256, (size_t)Nn*256,  nullptr, 0);
      else
        k_gemm2<512, true, true, 0, true, false, false><<<dim3(2, 32, 4), 256, 0, stream>>>(
            x3, x3, 2048, 512,  woh + (size_t)h*2048, wol + (size_t)h*2048, 8192, 512,
            ws + OFF_YP, nullptr, 256, (size_t)Nn*256,  nullptr, 0);
    }
  }

  k_gsum<<<dim3(32, 8), 256, 0, stream>>>(ws + OFF_YP, bout, batch, ws + OFF_PART);
  k_gfin<<<8, 256, 0, stream>>>(ws + OFF_PART, batch, out);
}